// Round 1
// baseline (492.199 us; speedup 1.0000x reference)
//
#include <hip/hip_runtime.h>
#include <stdint.h>

typedef unsigned short u16;
using us8   = __attribute__((ext_vector_type(8))) unsigned short;
using us4   = __attribute__((ext_vector_type(4))) unsigned short;
using bf16x8 = __attribute__((ext_vector_type(8))) __bf16;
using f32x4 = __attribute__((ext_vector_type(4))) float;

#define DEV static __device__ __forceinline__

DEV float bf2f(u16 u) { union { uint32_t i; float f; } v; v.i = (uint32_t)u << 16; return v.f; }
DEV u16 f2bf(float f) {
    union { float f; uint32_t i; } v; v.f = f;
    uint32_t u = v.i;
    return (u16)((u + 0x7FFFu + ((u >> 16) & 1u)) >> 16);
}

// async global->LDS 16B copy: lane l writes LDS at (uniform base) + l*16B.
DEV void async16(const u16* g, u16* ldsbase)
{
    __builtin_amdgcn_global_load_lds((const __attribute__((address_space(1))) void*)g,
                                     (__attribute__((address_space(3))) void*)ldsbase, 16, 0, 0);
}

// ---------------------------------------------------------------------------
// Fused dtype detection: 18 blocks, one per input tensor.
// ---------------------------------------------------------------------------
struct DetectArgs { const void* p[18]; int nw[18]; };

__global__ __launch_bounds__(256) void k_detect_all(DetectArgs a, int* flags)
{
    const int b = blockIdx.x;
    const int t = threadIdx.x;
    __shared__ int cnt[4];
    if (t < 4) cnt[t] = 0;
    __syncthreads();
    if (b == 1) {
        const uint8_t* m = (const uint8_t*)a.p[1];
        int c0 = 0, c1 = 0, c2 = 0, c3 = 0;
        for (int i = t; i < 4096; i += 256) {
            uint8_t v = m[i];
            int mod = i & 3;
            if (v == 0x3F && mod == 1) c0++;
            if (v == 0x3F && mod == 3) c1++;
            if (v == 1 && mod != 0) c2++;
            if (v == 1 && mod == 0) c3++;
        }
        atomicAdd(&cnt[0], c0); atomicAdd(&cnt[1], c1); atomicAdd(&cnt[2], c2); atomicAdd(&cnt[3], c3);
        __syncthreads();
        if (t == 0) {
            int mf;
            if (cnt[0] > 0) mf = 2;
            else if (cnt[1] > 0) mf = 3;
            else if (cnt[2] > 0) mf = 0;
            else if (cnt[3] > 0) mf = 1;
            else mf = 0;
            flags[1] = mf;
        }
    } else {
        const u16* p = (const u16*)a.p[b];
        int nw = a.nw[b];
        int nze = 0, pe = 0, nzo = 0;
        for (int i = t; i < nw; i += 256) {
            u16 w = p[i];
            if (w == 0) continue;
            int e = (w >> 7) & 0xFF;
            bool pl = (e >= 90 && e <= 140);
            if ((i & 1) == 0) { nze++; if (pl) pe++; }
            else nzo++;
        }
        atomicAdd(&cnt[0], nze); atomicAdd(&cnt[1], pe); atomicAdd(&cnt[2], nzo);
        __syncthreads();
        if (t == 0) {
            int f;
            if (cnt[0] > 0)      f = (cnt[1] * 10 >= cnt[0] * 6) ? 2 : 3;
            else if (cnt[2] > 0) f = 3;
            else                 f = 2;
            flags[b] = f;
        }
    }
}

__global__ __launch_bounds__(256) void k_expand_mask(const void* mask, const int* flag, float* mb)
{
    int i = blockIdx.x * 256 + threadIdx.x;
    if (i >= 4096) return;
    int f = *flag;
    bool on;
    if (f == 0)      on = ((const uint8_t*)mask)[i]  != 0;
    else if (f == 1) on = ((const int*)mask)[i]      != 0;
    else if (f == 2) on = ((const u16*)mask)[i]      != 0;
    else             on = ((const uint32_t*)mask)[i] != 0;
    mb[i] = on ? -1e9f : 0.0f;
}

__global__ __launch_bounds__(256) void k_convert_bf(const void* src, u16* dst, int n, const int* flag)
{
    int i = blockIdx.x * 256 + threadIdx.x;
    if (i >= n) return;
    if (*flag == 2) dst[i] = ((const u16*)src)[i];
    else            dst[i] = f2bf(((const float*)src)[i]);
}

// ---------------------------------------------------------------------------
// Fused LDS-tiled weight transposes
// ---------------------------------------------------------------------------
struct TransArgs { const void* src[6]; u16* dst[6]; int R[6]; int C[6]; int flagidx[6]; int tstart[7]; };

__global__ __launch_bounds__(256) void k_transpose_all(TransArgs a, const int* flags)
{
    const int tb = blockIdx.x;
    int s = 0;
    while (tb >= a.tstart[s + 1]) s++;
    const int lt = tb - a.tstart[s];
    const int R = a.R[s], C = a.C[s];
    const int tilesX = C >> 5;
    const int ti = lt / tilesX, tj = lt - ti * tilesX;
    const int r0 = ti * 32, c0 = tj * 32;
    const bool isbf = (flags[a.flagidx[s]] == 2);
    const int t = threadIdx.x;
    const int j = t & 31, i0 = t >> 5;
    __shared__ u16 tile[32][33];
#pragma unroll
    for (int p = 0; p < 4; p++) {
        int r = r0 + i0 + p * 8;
        size_t idx = (size_t)r * C + c0 + j;
        u16 v = isbf ? ((const u16*)a.src[s])[idx] : f2bf(((const float*)a.src[s])[idx]);
        tile[i0 + p * 8][j] = v;
    }
    __syncthreads();
    u16* dst = a.dst[s];
#pragma unroll
    for (int p = 0; p < 4; p++) {
        int c = i0 + p * 8;
        dst[(size_t)(c0 + c) * R + r0 + j] = tile[j][c];
    }
}

// ---------------------------------------------------------------------------
// Fused param converts
// ---------------------------------------------------------------------------
struct ConvArgs { const void* src[10]; int flagidx[10]; int off[10]; int n[10]; };

__global__ __launch_bounds__(256) void k_convert_params(ConvArgs a, const int* flags, float* par)
{
    int i = blockIdx.x * 256 + threadIdx.x;
    if (i >= 11264) return;
    int s = 0;
    while (s < 9 && i >= a.off[s] + a.n[s]) s++;
    int j = i - a.off[s];
    float v;
    if (flags[a.flagidx[s]] == 2) v = bf2f(((const u16*)a.src[s])[j]);
    else                          v = ((const float*)a.src[s])[j];
    par[i] = v;
}

// ---------------------------------------------------------------------------
// MFMA GEMM core, BK=64, async global->LDS staging with XOR-swizzled layout.
// C(M x N) = A(M x K, lda) * Bt(N x K, ldb)^T. fp32 accum. 256 threads.
// LDS tile: BM(/BN) rows x 64 cols bf16, rows stride 64 el (128 B), row r's
// 8-col chunk j stored at slot j^(r&7)  ->  fragment ds_read_b128 hits all 32
// banks with 2 lanes/bank (free).  Staged in 1 KB chunks of 8 rows: lane l
// loads row chunk*8 + l/8, col-chunk (l&7)^(l>>3).
// K must be a multiple of 64. BM, BN multiples of 32.
// ---------------------------------------------------------------------------
template<int BM, int BN, int WR, int WC, int TM, int TN>
DEV void gemm_tile(const u16* __restrict__ A, int lda,
                   const u16* __restrict__ Bt, int ldb, int K,
                   u16* As, u16* Bs, f32x4 (&acc)[TM][TN])
{
    const int t = threadIdx.x;
    const int lane = t & 63;
    const int wave = t >> 6;
    const int wr = wave / WC;
    const int wc = wave % WC;
    const int m16 = lane & 15;
    const int quad = lane >> 4;
    const int lr8 = lane >> 3;                 // 0..7 row within 8-row chunk
    const int lsw = (((lane & 7) ^ lr8) << 3); // swizzled col offset (elements)

#pragma unroll
    for (int i = 0; i < TM; i++)
#pragma unroll
        for (int j = 0; j < TN; j++) {
            acc[i][j][0] = 0.f; acc[i][j][1] = 0.f; acc[i][j][2] = 0.f; acc[i][j][3] = 0.f;
        }

    for (int kb = 0; kb < K; kb += 64) {
#pragma unroll
        for (int i = 0; i < BM / 32; i++) {
            int chunk = wave * (BM / 32) + i;
            int r = chunk * 8 + lr8;
            async16(A + (size_t)r * lda + kb + lsw, As + chunk * 512);
        }
#pragma unroll
        for (int i = 0; i < BN / 32; i++) {
            int chunk = wave * (BN / 32) + i;
            int r = chunk * 8 + lr8;
            async16(Bt + (size_t)r * ldb + kb + lsw, Bs + chunk * 512);
        }
        __syncthreads();   // drains vmcnt (incl. global_load_lds) before LDS reads
#pragma unroll
        for (int ks = 0; ks < 2; ks++) {
            bf16x8 af[TM], bfr[TN];
#pragma unroll
            for (int i = 0; i < TM; i++) {
                int row = wr * TM * 16 + i * 16 + m16;
                int jq = ks * 4 + quad;
                af[i] = *(const bf16x8*)(As + row * 64 + ((jq ^ (row & 7)) << 3));
            }
#pragma unroll
            for (int j = 0; j < TN; j++) {
                int row = wc * TN * 16 + j * 16 + m16;
                int jq = ks * 4 + quad;
                bfr[j] = *(const bf16x8*)(Bs + row * 64 + ((jq ^ (row & 7)) << 3));
            }
#pragma unroll
            for (int i = 0; i < TM; i++)
#pragma unroll
                for (int j = 0; j < TN; j++)
                    acc[i][j] = __builtin_amdgcn_mfma_f32_16x16x32_bf16(af[i], bfr[j], acc[i][j], 0, 0, 0);
        }
        __syncthreads();
    }
}

template<bool RELU>
__global__ __launch_bounds__(256) void k_gemm_std(const u16* __restrict__ A, int lda,
                                                  const u16* __restrict__ Bt, int ldb,
                                                  const float* __restrict__ bias,
                                                  u16* __restrict__ C, int ldc, int K)
{
    __shared__ __align__(16) u16 As[128 * 64];
    __shared__ __align__(16) u16 Bs[128 * 64];
    const u16* Ab = A + (size_t)blockIdx.y * 128 * lda;
    const u16* Bb = Bt + (size_t)blockIdx.x * 128 * ldb;
    f32x4 acc[4][4];
    gemm_tile<128, 128, 2, 2, 4, 4>(Ab, lda, Bb, ldb, K, As, Bs, acc);

    const int t = threadIdx.x, lane = t & 63, wave = t >> 6;
    const int wr = wave >> 1, wc = wave & 1, m16 = lane & 15, quad = lane >> 4;
    const size_t rowBase = (size_t)blockIdx.y * 128 + wr * 64;
    const int colBase = blockIdx.x * 128 + wc * 64;
#pragma unroll
    for (int tm = 0; tm < 4; tm++)
#pragma unroll
        for (int tn = 0; tn < 4; tn++) {
            int col = colBase + tn * 16 + m16;
            float bv = bias ? bias[col] : 0.f;
#pragma unroll
            for (int r = 0; r < 4; r++) {
                size_t row = rowBase + tm * 16 + quad * 4 + r;
                float v = acc[tm][tn][r] + bv;
                if (RELU) v = fmaxf(v, 0.f);
                C[row * (size_t)ldc + col] = f2bf(v);
            }
        }
}

// ---------------------------------------------------------------------------
// 256x256 deep-pipelined GEMM: 512 threads = 8 waves (2M x 4N), BK=64,
// double-buffered 128 KiB LDS (even K-tiles -> buf0, odd -> buf1), counted
// vmcnt (never drains to 0 in steady state), raw s_barrier (no vmcnt drain),
// setprio(1) around each 16-MFMA quadrant cluster.
// Per K-tile: 4 quadrant phases, each { stage 1 half-tile of tile kt+1 ||
// 12 ds_read_b128 || 16 MFMA }; at tile boundary stage tile kt+2's first
// half into the just-freed buffer, then s_waitcnt vmcnt(2).
// Correctness: buffer c is only written (a) into buf n while all waves read
// buf c this tile, or (b) into buf c after the q3 barrier, by which point
// every wave's LDS reads have retired (in-order lgkm retirement before the
// last MFMA that consumes them).
// ---------------------------------------------------------------------------
template<bool RELU>
__global__ __launch_bounds__(512, 2) void k_gemm256(const u16* __restrict__ A, int lda,
                                                    const u16* __restrict__ Bt, int ldb,
                                                    const float* __restrict__ bias,
                                                    u16* __restrict__ C, int ldc, int K)
{
    __shared__ __align__(16) u16 As[2][256 * 64];
    __shared__ __align__(16) u16 Bs[2][256 * 64];
    const int t = threadIdx.x;
    const int lane = t & 63, wave = t >> 6;
    const int wr = wave >> 2, wc = wave & 3;     // 2 x 4 wave grid
    const int m16 = lane & 15, quad = lane >> 4;
    const int lr8 = lane >> 3;
    const int lsw = (((lane & 7) ^ lr8) << 3);

    const u16* __restrict__ Ab = A + (size_t)blockIdx.y * 256 * lda;
    const u16* __restrict__ Bb = Bt + (size_t)blockIdx.x * 256 * ldb;

    f32x4 acc[8][4];
#pragma unroll
    for (int i = 0; i < 8; i++)
#pragma unroll
        for (int j = 0; j < 4; j++) {
            acc[i][j][0] = 0.f; acc[i][j][1] = 0.f; acc[i][j][2] = 0.f; acc[i][j][3] = 0.f;
        }

    const int NT = K >> 6;

    // stage half h of the K-tile at col kb into buffer c.
    // h=0/1: A rows 0-127 / 128-255; h=2/3: B rows 0-127 / 128-255.
    // Per wave: 2 global_load_lds (1 KB chunks of 8 rows each).
    auto stage_half = [&](int kb, int c, int h) {
        const u16* src = (h < 2) ? Ab : Bb;
        const int ld   = (h < 2) ? lda : ldb;
        u16* dst = (h < 2) ? &As[c][0] : &Bs[c][0];
#pragma unroll
        for (int r = 0; r < 2; r++) {
            int chunk = (h & 1) * 16 + r * 8 + wave;
            int row = chunk * 8 + lr8;
            async16(src + (size_t)row * ld + kb + lsw, dst + chunk * 512);
        }
    };

    // prologue: tile0 fully (8 loads/wave) + tile1 half0 (2 loads/wave)
#pragma unroll
    for (int h = 0; h < 4; h++) stage_half(0, 0, h);
    if (NT > 1) {
        stage_half(64, 1, 0);
        asm volatile("s_waitcnt vmcnt(2)" ::: "memory");   // tile0's 8 retired
    } else {
        asm volatile("s_waitcnt vmcnt(0)" ::: "memory");
    }
    asm volatile("s_barrier" ::: "memory");

    for (int kt = 0; kt < NT; ++kt) {
        const int c = kt & 1, n = c ^ 1;
        const int kb1 = (kt + 1) << 6;
        const bool st1 = (kt + 1 < NT);
#pragma unroll
        for (int q = 0; q < 4; q++) {
            if (st1 && q < 3) stage_half(kb1, n, q + 1);   // halves 1..3 of tile kt+1
            const int mq = q >> 1, nq = q & 1;
            bf16x8 af[2][4], bfr[2][2];
#pragma unroll
            for (int ks = 0; ks < 2; ks++) {
                int jq = ks * 4 + quad;
#pragma unroll
                for (int i = 0; i < 4; i++) {
                    int row = wr * 128 + (mq * 4 + i) * 16 + m16;
                    af[ks][i] = *(const bf16x8*)(&As[c][row * 64 + ((jq ^ (row & 7)) << 3)]);
                }
#pragma unroll
                for (int j = 0; j < 2; j++) {
                    int row = wc * 64 + (nq * 2 + j) * 16 + m16;
                    bfr[ks][j] = *(const bf16x8*)(&Bs[c][row * 64 + ((jq ^ (row & 7)) << 3)]);
                }
            }
            __builtin_amdgcn_s_setprio(1);
#pragma unroll
            for (int ks = 0; ks < 2; ks++)
#pragma unroll
                for (int i = 0; i < 4; i++)
#pragma unroll
                    for (int j = 0; j < 2; j++)
                        acc[mq * 4 + i][nq * 2 + j] =
                            __builtin_amdgcn_mfma_f32_16x16x32_bf16(af[ks][i], bfr[ks][j],
                                                                    acc[mq * 4 + i][nq * 2 + j], 0, 0, 0);
            __builtin_amdgcn_s_setprio(0);
            asm volatile("s_barrier" ::: "memory");
        }
        // tile boundary: buf c is free; stage tile kt+2's half0 there, then
        // counted wait -> tile kt+1's 8 loads retired, 2 newest stay in flight.
        if (kt + 2 < NT) {
            stage_half((kt + 2) << 6, c, 0);
            asm volatile("s_waitcnt vmcnt(2)" ::: "memory");
        } else {
            asm volatile("s_waitcnt vmcnt(0)" ::: "memory");
        }
        asm volatile("s_barrier" ::: "memory");
    }

    const size_t rowBase = (size_t)blockIdx.y * 256 + wr * 128;
    const int colBase = blockIdx.x * 256 + wc * 64;
#pragma unroll
    for (int f = 0; f < 8; f++)
#pragma unroll
        for (int tn = 0; tn < 4; tn++) {
            int col = colBase + tn * 16 + m16;
            float bv = bias ? bias[col] : 0.f;
#pragma unroll
            for (int r = 0; r < 4; r++) {
                size_t row = rowBase + f * 16 + quad * 4 + r;
                float v = acc[f][tn][r] + bv;
                if (RELU) v = fmaxf(v, 0.f);
                C[row * (size_t)ldc + col] = f2bf(v);
            }
        }
}

// Fused QKV: grid (4, 64, 6); z -> (g = z/3, mat = z%3). M=8192 N=512 K=512.
__global__ __launch_bounds__(256) void k_gemm_qkv(const u16* __restrict__ y_c,
                                                  const u16* __restrict__ WqT,
                                                  const u16* __restrict__ WkT,
                                                  const u16* __restrict__ WvT,
                                                  const float* __restrict__ biases,
                                                  u16* __restrict__ qp, u16* __restrict__ kp, u16* __restrict__ vp)
{
    __shared__ __align__(16) u16 As[128 * 64];
    __shared__ __align__(16) u16 Bs[128 * 64];
    const int z = blockIdx.z;
    const int mat = z % 3, g = z / 3;
    const u16* Bt = (mat == 0) ? WqT : (mat == 1) ? WkT : WvT;
    u16* out = ((mat == 0) ? qp : (mat == 1) ? kp : vp) + (size_t)g * 4194304;
    const float* bias = biases + mat * 512;
    const u16* Ab = y_c + g * 512 + (size_t)blockIdx.y * 128 * 1024;
    const u16* Bb = Bt + (size_t)blockIdx.x * 128 * 512;
    f32x4 acc[4][4];
    gemm_tile<128, 128, 2, 2, 4, 4>(Ab, 1024, Bb, 512, 512, As, Bs, acc);

    const int t = threadIdx.x, lane = t & 63, wave = t >> 6;
    const int wr = wave >> 1, wc = wave & 1, m16 = lane & 15, quad = lane >> 4;
    const size_t rowBase = (size_t)blockIdx.y * 128 + wr * 64;
    const int colBase = blockIdx.x * 128 + wc * 64;
#pragma unroll
    for (int tm = 0; tm < 4; tm++)
#pragma unroll
        for (int tn = 0; tn < 4; tn++) {
            int col = colBase + tn * 16 + m16;
            float bv = bias[col];
#pragma unroll
            for (int r = 0; r < 4; r++) {
                size_t row = rowBase + tm * 16 + quad * 4 + r;
                out[row * 512 + col] = f2bf(acc[tm][tn][r] + bv);
            }
        }
}

// ---------------------------------------------------------------------------
// Fused scores + mask + softmax -> P (bf16). Grid (4, 512). K=64 (one iter).
// ---------------------------------------------------------------------------
__global__ __launch_bounds__(256) void k_attn_scores(const u16* __restrict__ qproj,
                                                     const u16* __restrict__ kproj,
                                                     const float* __restrict__ maskb,
                                                     u16* __restrict__ P)
{
    __shared__ __align__(16) u16 As[64 * 64];
    __shared__ __align__(16) u16 Bs[256 * 64];
    __shared__ float smax[64][5];
    __shared__ float ssum[64][5];
    const int rt = blockIdx.x;
    const int z = blockIdx.y;
    const int bg = z >> 4, h = z & 15, hbit = h >> 3, hlow = h & 7;
    const int b = bg & 15;
    const size_t base = (size_t)bg * 262144 + (size_t)hbit * 512 + (size_t)hlow * 64;
    const u16* A = qproj + base + (size_t)rt * 64 * 1024;
    const u16* B = kproj + base;
    f32x4 acc[4][4];
    gemm_tile<64, 256, 1, 4, 4, 4>(A, 1024, B, 1024, 64, As, Bs, acc);

    const int t = threadIdx.x, lane = t & 63, wc = t >> 6;
    const int m16 = lane & 15, quad = lane >> 4;

    float mb[4];
#pragma unroll
    for (int j = 0; j < 4; j++) mb[j] = maskb[b * 256 + wc * 64 + j * 16 + m16];
#pragma unroll
    for (int i = 0; i < 4; i++)
#pragma unroll
        for (int j = 0; j < 4; j++)
#pragma unroll
            for (int r = 0; r < 4; r++)
                acc[i][j][r] = acc[i][j][r] * 0.125f + mb[j];

#pragma unroll
    for (int i = 0; i < 4; i++)
#pragma unroll
        for (int r = 0; r < 4; r++) {
            float mm = fmaxf(fmaxf(acc[i][0][r], acc[i][1][r]), fmaxf(acc[i][2][r], acc[i][3][r]));
            mm = fmaxf(mm, __shfl_xor(mm, 1));
            mm = fmaxf(mm, __shfl_xor(mm, 2));
            mm = fmaxf(mm, __shfl_xor(mm, 4));
            mm = fmaxf(mm, __shfl_xor(mm, 8));
            if (m16 == 0) smax[i * 16 + quad * 4 + r][wc] = mm;
        }
    __syncthreads();
    float mrow[4][4];
#pragma unroll
    for (int i = 0; i < 4; i++)
#pragma unroll
        for (int r = 0; r < 4; r++) {
            int row = i * 16 + quad * 4 + r;
            mrow[i][r] = fmaxf(fmaxf(smax[row][0], smax[row][1]), fmaxf(smax[row][2], smax[row][3]));
        }
#pragma unroll
    for (int i = 0; i < 4; i++)
#pragma unroll
        for (int r = 0; r < 4; r++) {
            float s = 0.f;
#pragma unroll
            for (int j = 0; j < 4; j++) {
                float e = __expf(acc[i][j][r] - mrow[i][r]);
                acc[i][j][r] = e;
                s += e;
            }
            s += __shfl_xor(s, 1);
            s += __shfl_xor(s, 2);
            s += __shfl_xor(s, 4);
            s += __shfl_xor(s, 8);
            if (m16 == 0) ssum[i * 16 + quad * 4 + r][wc] = s;
        }
    __syncthreads();
    u16* out = P + (size_t)z * 65536 + (size_t)rt * 64 * 256;
#pragma unroll
    for (int i = 0; i < 4; i++)
#pragma unroll
        for (int r = 0; r < 4; r++) {
            int row = i * 16 + quad * 4 + r;
            float inv = 1.0f / (ssum[row][0] + ssum[row][1] + ssum[row][2] + ssum[row][3]);
#pragma unroll
            for (int j = 0; j < 4; j++) {
                int col = wc * 64 + j * 16 + m16;
                out[(size_t)row * 256 + col] = f2bf(acc[i][j][r] * inv);
            }
        }
}

// vT[(bg*16+h)*64 + dh][s] = vproj[bg][l=2s+hbit][hlow*64+dh]
__global__ __launch_bounds__(256) void k_transpose_v(const u16* __restrict__ vproj, u16* __restrict__ vT)
{
    __shared__ __align__(16) u16 tile[64 * 72];
    const int lt = blockIdx.x, hlow = blockIdx.y, bg = blockIdx.z;
    const int t = threadIdx.x;
    {
        int rl = t >> 2, c16 = (t & 3) * 16;
        const u16* src = vproj + (size_t)bg * 262144 + (size_t)(lt * 64 + rl) * 512 + hlow * 64 + c16;
        *(us8*)(tile + rl * 72 + c16)     = *(const us8*)src;
        *(us8*)(tile + rl * 72 + c16 + 8) = *(const us8*)(src + 8);
    }
    __syncthreads();
    const int lanej = t & 31, grp = t >> 5;
#pragma unroll
    for (int hbit = 0; hbit < 2; hbit++) {
        int h = hbit * 8 + hlow;
#pragma unroll
        for (int i = 0; i < 8; i++) {
            int dh = grp + i * 8;
            u16 val = tile[(2 * lanej + hbit) * 72 + dh];
            vT[(((size_t)bg * 16 + h) * 64 + dh) * 256 + lt * 32 + lanej] = val;
        }
    }
}

// ctx = P V, scatter into attedpre (B,L,H). Grid (2, 512). K=256.
__global__ __launch_bounds__(256) void k_gemm_ctx(const u16* __restrict__ P,
                                                  const u16* __restrict__ vT,
                                                  u16* __restrict__ attedpre)
{
    __shared__ __align__(16) u16 As[128 * 64];
    __shared__ __align__(16) u16 Bs[64 * 64];
    const int z = blockIdx.y;
    const u16* A = P + (size_t)z * 65536 + (size_t)blockIdx.x * 128 * 256;
    const u16* B = vT + (size_t)z * 16384;
    f32x4 acc[2][4];
    gemm_tile<128, 64, 4, 1, 2, 4>(A, 256, B, 256, 256, As, Bs, acc);

    const int t = threadIdx.x, lane = t & 63, wave = t >> 6;
    const int m16 = lane & 15, quad = lane >> 4;
    const int bg = z >> 4, h = z & 15;
    const int g = bg >> 4, b = bg & 15, hbit = h >> 3, hlow = h & 7;
    const int cBase = g * 512 + hlow * 64;
#pragma unroll
    for (int tm = 0; tm < 2; tm++)
#pragma unroll
        for (int tn = 0; tn < 4; tn++) {
            int dh = tn * 16 + m16;
#pragma unroll
            for (int r = 0; r < 4; r++) {
                int s = blockIdx.x * 128 + wave * 32 + tm * 16 + quad * 4 + r;
                int l = 2 * s + hbit;
                attedpre[((size_t)b * 512 + l) * 1024 + cBase + dh] = f2bf(acc[tm][tn][r]);
            }
        }
}

// Fused grouped FFN2: grid (8, 64). x -> (g = x>>2, xn = x&3).
__global__ __launch_bounds__(256) void k_gemm_ffn2(const u16* __restrict__ h1,
                                                   const u16* __restrict__ W2T,
                                                   const float* __restrict__ b2,
                                                   u16* __restrict__ out)
{
    __shared__ __align__(16) u16 As[128 * 64];
    __shared__ __align__(16) u16 Bs[128 * 64];
    const int xi = blockIdx.x;
    const int g = xi >> 2, xn = xi & 3;
    const u16* Ab = h1 + (size_t)blockIdx.y * 128 * 4096 + g * 2048;
    const u16* Bb = W2T + (size_t)xn * 128 * 2048;
    f32x4 acc[4][4];
    gemm_tile<128, 128, 2, 2, 4, 4>(Ab, 4096, Bb, 2048, 2048, As, Bs, acc);

    const int t = threadIdx.x, lane = t & 63, wave = t >> 6;
    const int wr = wave >> 1, wc = wave & 1, m16 = lane & 15, quad = lane >> 4;
    const size_t rowBase = (size_t)blockIdx.y * 128 + wr * 64;
    const int colg = xn * 128 + wc * 64;
#pragma unroll
    for (int tm = 0; tm < 4; tm++)
#pragma unroll
        for (int tn = 0; tn < 4; tn++) {
            int cg = colg + tn * 16 + m16;
            float bv = b2[cg];
#pragma unroll
            for (int r = 0; r < 4; r++) {
                size_t row = rowBase + tm * 16 + quad * 4 + r;
                out[row * 1024 + g * 512 + cg] = f2bf(acc[tm][tn][r] + bv);
            }
        }
}

// out = LN(x1 + x2) * gamma + beta over D=1024; one block per row.
template<int FINAL>
__global__ __launch_bounds__(256) void k_ln(const u16* __restrict__ x1, const u16* __restrict__ x2,
                                            const float* __restrict__ gamma, const float* __restrict__ beta,
                                            void* __restrict__ outv, const int* __restrict__ yflag)
{
    const size_t row = blockIdx.x;
    const int t = threadIdx.x;
    us4 a = *(const us4*)(x1 + row * 1024 + t * 4);
    us4 b = *(const us4*)(x2 + row * 1024 + t * 4);
    float v[4]; float s = 0.f, s2 = 0.f;
#pragma unroll
    for (int i = 0; i < 4; i++) { v[i] = bf2f(a[i]) + bf2f(b[i]); s += v[i]; s2 += v[i] * v[i]; }
#pragma unroll
    for (int off = 32; off > 0; off >>= 1) { s += __shfl_xor(s, off); s2 += __shfl_xor(s2, off); }
    __shared__ float red[8];
    const int lane = t & 63, wave = t >> 6;
    if (lane == 0) { red[wave] = s; red[wave + 4] = s2; }
    __syncthreads();
    s = red[0] + red[1] + red[2] + red[3];
    s2 = red[4] + red[5] + red[6] + red[7];
    float mean = s * (1.0f / 1024.0f);
    float var = fmaxf(s2 * (1.0f / 1024.0f) - mean * mean, 0.0f);
    float rs = rsqrtf(var + 1e-6f);
    float o[4];
#pragma unroll
    for (int i = 0; i < 4; i++) {
        int c = t * 4 + i;
        o[i] = (v[i] - mean) * rs * gamma[c] + beta[c];
    }
    bool f32out = FINAL && yflag && (*yflag == 3);
    if (f32out) {
        float* out = (float*)outv;
#pragma unroll
        for (int i = 0; i < 4; i++) out[row * 1024 + t * 4 + i] = o[i];
    } else {
        u16* out = (u16*)outv;
        us4 ov;
#pragma unroll
        for (int i = 0; i < 4; i++) ov[i] = f2bf(o[i]);
        *(us4*)(out + row * 1024 + t * 4) = ov;
    }
}

// ---------------------------------------------------------------------------
extern "C" void kernel_launch(void* const* d_in, const int* in_sizes, int n_in,
                              void* d_out, int out_size, void* d_ws, size_t ws_size,
                              hipStream_t stream)
{
    (void)in_sizes; (void)n_in; (void)out_size; (void)ws_size;
    const void* y    = d_in[0];
    const void* mask = d_in[1];
    const void* Wv = d_in[2];  const void* bv = d_in[3];
    const void* Wk = d_in[4];  const void* bk = d_in[5];
    const void* Wq = d_in[6];  const void* bq = d_in[7];
    const void* Wm = d_in[8];  const void* bm = d_in[9];
    const void* W1 = d_in[10]; const void* b1 = d_in[11];
    const void* W2 = d_in[12]; const void* b2 = d_in[13];
    const void* g1 = d_in[14]; const void* be1 = d_in[15];
    const void* g2 = d_in[16]; const void* be2 = d_in[17];

    char* ws = (char*)d_ws;
    size_t off = 0;
    auto alloc = [&](size_t bytes) { void* p = ws + off; off = (off + bytes + 255) & ~(size_t)255; return p; };

    int*   flags = (int*)alloc(32 * 4);
    float* maskb = (float*)alloc(16 * 256 * 4);
    float* par   = (float*)alloc(11264 * 4);
    u16* WqT  = (u16*)alloc((size_t)262144 * 2);
    u16* WkT  = (u16*)alloc((size_t)262144 * 2);
    u16* WvT  = (u16*)alloc((size_t)262144 * 2);
    u16* WmT  = (u16*)alloc((size_t)1048576 * 2);
    u16* W1T  = (u16*)alloc((size_t)4194304 * 2);
    u16* W2T  = (u16*)alloc((size_t)1048576 * 2);
    u16* y_c  = (u16*)alloc((size_t)8388608 * 2);
    u16* slotA = (u16*)alloc((size_t)8388608 * 2);   // qproj -> mergeout
    u16* slotB = (u16*)alloc((size_t)8388608 * 2);   // kproj -> y1
    u16* slotC = (u16*)alloc((size_t)8388608 * 2);   // vT -> ffout
    u16* slotD = (u16*)alloc((size_t)8388608 * 2);   // vproj -> attedpre
    u16* Pbig  = (u16*)alloc((size_t)33554432 * 2);  // P (64 MB) -> h1 (32 MB)

    float* p_bm  = par + 1536;
    float* p_b1  = par + 2560;
    float* p_b2  = par + 6656;
    float* p_g1  = par + 7168;
    float* p_be1 = par + 8192;
    float* p_g2  = par + 9216;
    float* p_be2 = par + 10240;

    DetectArgs da;
    {
        const void* srcs[18] = {y, mask, Wv, bv, Wk, bk, Wq, bq, Wm, bm, W1, b1, W2, b2, g1, be1, g2, be2};
        const int   nele[18] = {8388608, 4096, 262144, 512, 262144, 512, 262144, 512, 1048576, 1024,
                                4194304, 4096, 1048576, 512, 1024, 1024, 1024, 1024};
        for (int i = 0; i < 18; i++) { da.p[i] = srcs[i]; da.nw[i] = nele[i] < 4096 ? nele[i] : 4096; }
    }
    k_detect_all<<<18, 256, 0, stream>>>(da, flags);

    k_expand_mask<<<16, 256, 0, stream>>>(mask, flags + 1, maskb);
    k_convert_bf<<<32768, 256, 0, stream>>>(y, y_c, 8388608, flags + 0);

    TransArgs ta;
    {
        const void* s6[6] = {Wq, Wk, Wv, Wm, W1, W2};
        u16* d6[6] = {WqT, WkT, WvT, WmT, W1T, W2T};
        int R6[6] = {512, 512, 512, 1024, 1024, 2048};
        int C6[6] = {512, 512, 512, 1024, 4096, 512};
        int f6[6] = {6, 4, 2, 8, 10, 12};
        int ts[7] = {0, 256, 512, 768, 1792, 5888, 6912};
        for (int i = 0; i < 6; i++) { ta.src[i] = s6[i]; ta.dst[i] = d6[i]; ta.R[i] = R6[i]; ta.C[i] = C6[i]; ta.flagidx[i] = f6[i]; }
        for (int i = 0; i < 7; i++) ta.tstart[i] = ts[i];
    }
    k_transpose_all<<<6912, 256, 0, stream>>>(ta, flags);

    ConvArgs ca;
    {
        const void* s10[10] = {bq, bk, bv, bm, b1, b2, g1, be1, g2, be2};
        int f10[10] = {7, 5, 3, 9, 11, 13, 14, 15, 16, 17};
        int o10[10] = {0, 512, 1024, 1536, 2560, 6656, 7168, 8192, 9216, 10240};
        int n10[10] = {512, 512, 512, 1024, 4096, 512, 1024, 1024, 1024, 1024};
        for (int i = 0; i < 10; i++) { ca.src[i] = s10[i]; ca.flagidx[i] = f10[i]; ca.off[i] = o10[i]; ca.n[i] = n10[i]; }
    }
    k_convert_params<<<44, 256, 0, stream>>>(ca, flags, par);

    u16* qproj = slotA;
    u16* kproj = slotB;
    u16* vT    = slotC;
    u16* vproj = slotD;

    k_gemm_qkv<<<dim3(4, 64, 6), 256, 0, stream>>>(y_c, WqT, WkT, WvT, par, qproj, kproj, vproj);
    k_transpose_v<<<dim3(8, 8, 32), 256, 0, stream>>>(vproj, vT);

    u16* P = Pbig;
    k_attn_scores<<<dim3(4, 512), 256, 0, stream>>>(qproj, kproj, maskb, P);

    u16* attedpre = slotD;   // vproj dead
    k_gemm_ctx<<<dim3(2, 512), 256, 0, stream>>>(P, vT, attedpre);

    u16* mergeout = slotA;   // qproj dead
    k_gemm_std<false><<<dim3(8, 64), 256, 0, stream>>>(attedpre, 1024, WmT, 1024, p_bm, mergeout, 1024, 1024);

    u16* y1 = slotB;         // kproj dead
    k_ln<0><<<8192, 256, 0, stream>>>(y_c, mergeout, p_g1, p_be1, y1, nullptr);

    u16* h1 = Pbig;          // P dead after ctx
    k_gemm256<true><<<dim3(16, 32), 512, 0, stream>>>(y1, 1024, W1T, 1024, p_b1, h1, 4096, 1024);

    u16* ffout = slotC;      // vT dead
    k_gemm_ffn2<<<dim3(8, 64), 256, 0, stream>>>(h1, W2T, p_b2, ffout);

    k_ln<1><<<8192, 256, 0, stream>>>(y1, ffout, p_g2, p_be2, d_out, flags + 0);
}

// Round 2
// 486.629 us; speedup vs baseline: 1.0114x; 1.0114x over previous
//
#include <hip/hip_runtime.h>
#include <stdint.h>

typedef unsigned short u16;
using us8   = __attribute__((ext_vector_type(8))) unsigned short;
using us4   = __attribute__((ext_vector_type(4))) unsigned short;
using bf16x8 = __attribute__((ext_vector_type(8))) __bf16;
using f32x4 = __attribute__((ext_vector_type(4))) float;

#define DEV static __device__ __forceinline__

DEV float bf2f(u16 u) { union { uint32_t i; float f; } v; v.i = (uint32_t)u << 16; return v.f; }
DEV u16 f2bf(float f) {
    union { float f; uint32_t i; } v; v.f = f;
    uint32_t u = v.i;
    return (u16)((u + 0x7FFFu + ((u >> 16) & 1u)) >> 16);
}

// async global->LDS 16B copy: lane l writes LDS at (uniform base) + l*16B.
DEV void async16(const u16* g, u16* ldsbase)
{
    __builtin_amdgcn_global_load_lds((const __attribute__((address_space(1))) void*)g,
                                     (__attribute__((address_space(3))) void*)ldsbase, 16, 0, 0);
}

// ---------------------------------------------------------------------------
// Fused dtype detection: 18 blocks, one per input tensor.
// ---------------------------------------------------------------------------
struct DetectArgs { const void* p[18]; int nw[18]; };

__global__ __launch_bounds__(256) void k_detect_all(DetectArgs a, int* flags)
{
    const int b = blockIdx.x;
    const int t = threadIdx.x;
    __shared__ int cnt[4];
    if (t < 4) cnt[t] = 0;
    __syncthreads();
    if (b == 1) {
        const uint8_t* m = (const uint8_t*)a.p[1];
        int c0 = 0, c1 = 0, c2 = 0, c3 = 0;
        for (int i = t; i < 4096; i += 256) {
            uint8_t v = m[i];
            int mod = i & 3;
            if (v == 0x3F && mod == 1) c0++;
            if (v == 0x3F && mod == 3) c1++;
            if (v == 1 && mod != 0) c2++;
            if (v == 1 && mod == 0) c3++;
        }
        atomicAdd(&cnt[0], c0); atomicAdd(&cnt[1], c1); atomicAdd(&cnt[2], c2); atomicAdd(&cnt[3], c3);
        __syncthreads();
        if (t == 0) {
            int mf;
            if (cnt[0] > 0) mf = 2;
            else if (cnt[1] > 0) mf = 3;
            else if (cnt[2] > 0) mf = 0;
            else if (cnt[3] > 0) mf = 1;
            else mf = 0;
            flags[1] = mf;
        }
    } else {
        const u16* p = (const u16*)a.p[b];
        int nw = a.nw[b];
        int nze = 0, pe = 0, nzo = 0;
        for (int i = t; i < nw; i += 256) {
            u16 w = p[i];
            if (w == 0) continue;
            int e = (w >> 7) & 0xFF;
            bool pl = (e >= 90 && e <= 140);
            if ((i & 1) == 0) { nze++; if (pl) pe++; }
            else nzo++;
        }
        atomicAdd(&cnt[0], nze); atomicAdd(&cnt[1], pe); atomicAdd(&cnt[2], nzo);
        __syncthreads();
        if (t == 0) {
            int f;
            if (cnt[0] > 0)      f = (cnt[1] * 10 >= cnt[0] * 6) ? 2 : 3;
            else if (cnt[2] > 0) f = 3;
            else                 f = 2;
            flags[b] = f;
        }
    }
}

__global__ __launch_bounds__(256) void k_expand_mask(const void* mask, const int* flag, float* mb)
{
    int i = blockIdx.x * 256 + threadIdx.x;
    if (i >= 4096) return;
    int f = *flag;
    bool on;
    if (f == 0)      on = ((const uint8_t*)mask)[i]  != 0;
    else if (f == 1) on = ((const int*)mask)[i]      != 0;
    else if (f == 2) on = ((const u16*)mask)[i]      != 0;
    else             on = ((const uint32_t*)mask)[i] != 0;
    mb[i] = on ? -1e9f : 0.0f;
}

__global__ __launch_bounds__(256) void k_convert_bf(const void* src, u16* dst, int n, const int* flag)
{
    int i = blockIdx.x * 256 + threadIdx.x;
    if (i >= n) return;
    if (*flag == 2) dst[i] = ((const u16*)src)[i];
    else            dst[i] = f2bf(((const float*)src)[i]);
}

// ---------------------------------------------------------------------------
// Fused LDS-tiled weight transposes
// ---------------------------------------------------------------------------
struct TransArgs { const void* src[6]; u16* dst[6]; int R[6]; int C[6]; int flagidx[6]; int tstart[7]; };

__global__ __launch_bounds__(256) void k_transpose_all(TransArgs a, const int* flags)
{
    const int tb = blockIdx.x;
    int s = 0;
    while (tb >= a.tstart[s + 1]) s++;
    const int lt = tb - a.tstart[s];
    const int R = a.R[s], C = a.C[s];
    const int tilesX = C >> 5;
    const int ti = lt / tilesX, tj = lt - ti * tilesX;
    const int r0 = ti * 32, c0 = tj * 32;
    const bool isbf = (flags[a.flagidx[s]] == 2);
    const int t = threadIdx.x;
    const int j = t & 31, i0 = t >> 5;
    __shared__ u16 tile[32][33];
#pragma unroll
    for (int p = 0; p < 4; p++) {
        int r = r0 + i0 + p * 8;
        size_t idx = (size_t)r * C + c0 + j;
        u16 v = isbf ? ((const u16*)a.src[s])[idx] : f2bf(((const float*)a.src[s])[idx]);
        tile[i0 + p * 8][j] = v;
    }
    __syncthreads();
    u16* dst = a.dst[s];
#pragma unroll
    for (int p = 0; p < 4; p++) {
        int c = i0 + p * 8;
        dst[(size_t)(c0 + c) * R + r0 + j] = tile[j][c];
    }
}

// ---------------------------------------------------------------------------
// Fused param converts
// ---------------------------------------------------------------------------
struct ConvArgs { const void* src[10]; int flagidx[10]; int off[10]; int n[10]; };

__global__ __launch_bounds__(256) void k_convert_params(ConvArgs a, const int* flags, float* par)
{
    int i = blockIdx.x * 256 + threadIdx.x;
    if (i >= 11264) return;
    int s = 0;
    while (s < 9 && i >= a.off[s] + a.n[s]) s++;
    int j = i - a.off[s];
    float v;
    if (flags[a.flagidx[s]] == 2) v = bf2f(((const u16*)a.src[s])[j]);
    else                          v = ((const float*)a.src[s])[j];
    par[i] = v;
}

// ---------------------------------------------------------------------------
// MFMA GEMM core, BK=64, async global->LDS staging with XOR-swizzled layout.
// C(M x N) = A(M x K, lda) * Bt(N x K, ldb)^T. fp32 accum. 256 threads.
// ---------------------------------------------------------------------------
template<int BM, int BN, int WR, int WC, int TM, int TN>
DEV void gemm_tile(const u16* __restrict__ A, int lda,
                   const u16* __restrict__ Bt, int ldb, int K,
                   u16* As, u16* Bs, f32x4 (&acc)[TM][TN])
{
    const int t = threadIdx.x;
    const int lane = t & 63;
    const int wave = t >> 6;
    const int wr = wave / WC;
    const int wc = wave % WC;
    const int m16 = lane & 15;
    const int quad = lane >> 4;
    const int lr8 = lane >> 3;                 // 0..7 row within 8-row chunk
    const int lsw = (((lane & 7) ^ lr8) << 3); // swizzled col offset (elements)

#pragma unroll
    for (int i = 0; i < TM; i++)
#pragma unroll
        for (int j = 0; j < TN; j++) {
            acc[i][j][0] = 0.f; acc[i][j][1] = 0.f; acc[i][j][2] = 0.f; acc[i][j][3] = 0.f;
        }

    for (int kb = 0; kb < K; kb += 64) {
#pragma unroll
        for (int i = 0; i < BM / 32; i++) {
            int chunk = wave * (BM / 32) + i;
            int r = chunk * 8 + lr8;
            async16(A + (size_t)r * lda + kb + lsw, As + chunk * 512);
        }
#pragma unroll
        for (int i = 0; i < BN / 32; i++) {
            int chunk = wave * (BN / 32) + i;
            int r = chunk * 8 + lr8;
            async16(Bt + (size_t)r * ldb + kb + lsw, Bs + chunk * 512);
        }
        __syncthreads();   // drains vmcnt (incl. global_load_lds) before LDS reads
#pragma unroll
        for (int ks = 0; ks < 2; ks++) {
            bf16x8 af[TM], bfr[TN];
#pragma unroll
            for (int i = 0; i < TM; i++) {
                int row = wr * TM * 16 + i * 16 + m16;
                int jq = ks * 4 + quad;
                af[i] = *(const bf16x8*)(As + row * 64 + ((jq ^ (row & 7)) << 3));
            }
#pragma unroll
            for (int j = 0; j < TN; j++) {
                int row = wc * TN * 16 + j * 16 + m16;
                int jq = ks * 4 + quad;
                bfr[j] = *(const bf16x8*)(Bs + row * 64 + ((jq ^ (row & 7)) << 3));
            }
#pragma unroll
            for (int i = 0; i < TM; i++)
#pragma unroll
                for (int j = 0; j < TN; j++)
                    acc[i][j] = __builtin_amdgcn_mfma_f32_16x16x32_bf16(af[i], bfr[j], acc[i][j], 0, 0, 0);
        }
        __syncthreads();
    }
}

template<bool RELU>
__global__ __launch_bounds__(256) void k_gemm_std(const u16* __restrict__ A, int lda,
                                                  const u16* __restrict__ Bt, int ldb,
                                                  const float* __restrict__ bias,
                                                  u16* __restrict__ C, int ldc, int K)
{
    __shared__ __align__(16) u16 As[128 * 64];
    __shared__ __align__(16) u16 Bs[128 * 64];
    const u16* Ab = A + (size_t)blockIdx.y * 128 * lda;
    const u16* Bb = Bt + (size_t)blockIdx.x * 128 * ldb;
    f32x4 acc[4][4];
    gemm_tile<128, 128, 2, 2, 4, 4>(Ab, lda, Bb, ldb, K, As, Bs, acc);

    const int t = threadIdx.x, lane = t & 63, wave = t >> 6;
    const int wr = wave >> 1, wc = wave & 1, m16 = lane & 15, quad = lane >> 4;
    const size_t rowBase = (size_t)blockIdx.y * 128 + wr * 64;
    const int colBase = blockIdx.x * 128 + wc * 64;
#pragma unroll
    for (int tm = 0; tm < 4; tm++)
#pragma unroll
        for (int tn = 0; tn < 4; tn++) {
            int col = colBase + tn * 16 + m16;
            float bv = bias ? bias[col] : 0.f;
#pragma unroll
            for (int r = 0; r < 4; r++) {
                size_t row = rowBase + tm * 16 + quad * 4 + r;
                float v = acc[tm][tn][r] + bv;
                if (RELU) v = fmaxf(v, 0.f);
                C[row * (size_t)ldc + col] = f2bf(v);
            }
        }
}

// ---------------------------------------------------------------------------
// 256x256 pipelined GEMM, v2 (read-once phases): 512 threads = 8 waves
// (2M x 4N), BK=64, double-buffered 128 KiB LDS. Per K-tile: TWO phases,
// each read-once (phase A: 8 B-frags + 8 A-low frags -> 32 MFMA; phase B:
// 8 A-high frags, B reused from registers -> 32 MFMA). 24 ds_read_b128 /
// wave / tile (minimum), vs 48 in v1 (v1 was LDS-read-BW-bound: 4.5k cy
// LDS vs 2.5k cy MFMA per CU-tile).
// Sync: 2 s_barrier + 1 counted vmcnt per K-tile, nothing intra-phase.
// Prefetch: tile kt+1's B-halves issued at phase-A start (2 phases of
// cover); tile kt+2's A-halves issued at the boundary into the freed
// buffer (a full tile of cover); steady-state vmcnt(4) retires exactly
// tile kt+1's 8 loads while kt+2's 4 stay in flight.
// Hazards: phases only READ buf c; all writes to buf c occur after the
// boundary barrier (readers' ds_reads retired: their MFMA consumers
// executed => lgkmcnt passed). Writes to buf n during phases touch a
// buffer nobody reads this iteration.
// ---------------------------------------------------------------------------
template<bool RELU>
__global__ __launch_bounds__(512, 2) void k_gemm256(const u16* __restrict__ A, int lda,
                                                    const u16* __restrict__ Bt, int ldb,
                                                    const float* __restrict__ bias,
                                                    u16* __restrict__ C, int ldc, int K)
{
    __shared__ __align__(16) u16 As[2][256 * 64];
    __shared__ __align__(16) u16 Bs[2][256 * 64];
    const int t = threadIdx.x;
    const int lane = t & 63, wave = t >> 6;
    const int wr = wave >> 2, wc = wave & 3;     // 2 x 4 wave grid
    const int m16 = lane & 15, quad = lane >> 4;
    const int lr8 = lane >> 3;
    const int lsw = (((lane & 7) ^ lr8) << 3);

    const u16* __restrict__ Ab = A + (size_t)blockIdx.y * 256 * lda;
    const u16* __restrict__ Bb = Bt + (size_t)blockIdx.x * 256 * ldb;

    f32x4 acc[8][4];
#pragma unroll
    for (int i = 0; i < 8; i++)
#pragma unroll
        for (int j = 0; j < 4; j++) {
            acc[i][j][0] = 0.f; acc[i][j][1] = 0.f; acc[i][j][2] = 0.f; acc[i][j][3] = 0.f;
        }

    const int NT = K >> 6;

    // stage half h of the K-tile at col kb into buffer c.
    // h=0/1: A rows 0-127 / 128-255; h=2/3: B rows 0-127 / 128-255.
    // Per wave: 2 global_load_lds (1 KB chunks of 8 rows each).
    auto stage_half = [&](int kb, int c, int h) {
        const u16* src = (h < 2) ? Ab : Bb;
        const int ld   = (h < 2) ? lda : ldb;
        u16* dst = (h < 2) ? &As[c][0] : &Bs[c][0];
#pragma unroll
        for (int r = 0; r < 2; r++) {
            int chunk = (h & 1) * 16 + r * 8 + wave;
            int row = chunk * 8 + lr8;
            async16(src + (size_t)row * ld + kb + lsw, dst + chunk * 512);
        }
    };

    // prologue: tile0 fully (8 loads/wave) + tile1 A-halves (4 loads/wave)
#pragma unroll
    for (int h = 0; h < 4; h++) stage_half(0, 0, h);
    if (NT > 1) {
        stage_half(64, 1, 0);
        stage_half(64, 1, 1);
        asm volatile("s_waitcnt vmcnt(4)" ::: "memory");   // tile0's 8 retired
    } else {
        asm volatile("s_waitcnt vmcnt(0)" ::: "memory");
    }
    asm volatile("s_barrier" ::: "memory");

    for (int kt = 0; kt < NT; ++kt) {
        const int c = kt & 1, n = c ^ 1;
        // issue tile kt+1's B-halves early (2 phases of cover before the wait)
        if (kt + 1 < NT) {
            const int kb1 = (kt + 1) << 6;
            stage_half(kb1, n, 2);
            stage_half(kb1, n, 3);
        }
        // ---- phase A: all B frags + A-low frags, 32 MFMA ----
        bf16x8 bfr[2][4], af[2][4];
#pragma unroll
        for (int ks = 0; ks < 2; ks++) {
            int jq = ks * 4 + quad;
#pragma unroll
            for (int j = 0; j < 4; j++) {
                int row = wc * 64 + j * 16 + m16;
                bfr[ks][j] = *(const bf16x8*)(&Bs[c][row * 64 + ((jq ^ (row & 7)) << 3)]);
            }
#pragma unroll
            for (int i = 0; i < 4; i++) {
                int row = wr * 128 + i * 16 + m16;
                af[ks][i] = *(const bf16x8*)(&As[c][row * 64 + ((jq ^ (row & 7)) << 3)]);
            }
        }
        __builtin_amdgcn_s_setprio(1);
#pragma unroll
        for (int ks = 0; ks < 2; ks++)
#pragma unroll
            for (int i = 0; i < 4; i++)
#pragma unroll
                for (int j = 0; j < 4; j++)
                    acc[i][j] = __builtin_amdgcn_mfma_f32_16x16x32_bf16(af[ks][i], bfr[ks][j],
                                                                        acc[i][j], 0, 0, 0);
        __builtin_amdgcn_s_setprio(0);
        // ---- phase B: A-high frags (B reused in registers), 32 MFMA ----
#pragma unroll
        for (int ks = 0; ks < 2; ks++) {
            int jq = ks * 4 + quad;
#pragma unroll
            for (int i = 0; i < 4; i++) {
                int row = wr * 128 + 64 + i * 16 + m16;
                af[ks][i] = *(const bf16x8*)(&As[c][row * 64 + ((jq ^ (row & 7)) << 3)]);
            }
        }
        __builtin_amdgcn_s_setprio(1);
#pragma unroll
        for (int ks = 0; ks < 2; ks++)
#pragma unroll
            for (int i = 0; i < 4; i++)
#pragma unroll
                for (int j = 0; j < 4; j++)
                    acc[4 + i][j] = __builtin_amdgcn_mfma_f32_16x16x32_bf16(af[ks][i], bfr[ks][j],
                                                                            acc[4 + i][j], 0, 0, 0);
        __builtin_amdgcn_s_setprio(0);
        // ---- boundary ----
        asm volatile("s_barrier" ::: "memory");            // buf-c readers done
        if (kt + 2 < NT) {
            const int kb2 = (kt + 2) << 6;
            stage_half(kb2, c, 0);                         // kt+2 A-halves into freed buf
            stage_half(kb2, c, 1);
            asm volatile("s_waitcnt vmcnt(4)" ::: "memory");   // retires tile kt+1's 8 loads
        } else {
            asm volatile("s_waitcnt vmcnt(0)" ::: "memory");
        }
        asm volatile("s_barrier" ::: "memory");            // tile kt+1 visible to all
    }

    const size_t rowBase = (size_t)blockIdx.y * 256 + wr * 128;
    const int colBase = blockIdx.x * 256 + wc * 64;
#pragma unroll
    for (int f = 0; f < 8; f++)
#pragma unroll
        for (int tn = 0; tn < 4; tn++) {
            int col = colBase + tn * 16 + m16;
            float bv = bias ? bias[col] : 0.f;
#pragma unroll
            for (int r = 0; r < 4; r++) {
                size_t row = rowBase + f * 16 + quad * 4 + r;
                float v = acc[f][tn][r] + bv;
                if (RELU) v = fmaxf(v, 0.f);
                C[row * (size_t)ldc + col] = f2bf(v);
            }
        }
}

// Fused QKV: grid (4, 64, 6); z -> (g = z/3, mat = z%3). M=8192 N=512 K=512.
__global__ __launch_bounds__(256) void k_gemm_qkv(const u16* __restrict__ y_c,
                                                  const u16* __restrict__ WqT,
                                                  const u16* __restrict__ WkT,
                                                  const u16* __restrict__ WvT,
                                                  const float* __restrict__ biases,
                                                  u16* __restrict__ qp, u16* __restrict__ kp, u16* __restrict__ vp)
{
    __shared__ __align__(16) u16 As[128 * 64];
    __shared__ __align__(16) u16 Bs[128 * 64];
    const int z = blockIdx.z;
    const int mat = z % 3, g = z / 3;
    const u16* Bt = (mat == 0) ? WqT : (mat == 1) ? WkT : WvT;
    u16* out = ((mat == 0) ? qp : (mat == 1) ? kp : vp) + (size_t)g * 4194304;
    const float* bias = biases + mat * 512;
    const u16* Ab = y_c + g * 512 + (size_t)blockIdx.y * 128 * 1024;
    const u16* Bb = Bt + (size_t)blockIdx.x * 128 * 512;
    f32x4 acc[4][4];
    gemm_tile<128, 128, 2, 2, 4, 4>(Ab, 1024, Bb, 512, 512, As, Bs, acc);

    const int t = threadIdx.x, lane = t & 63, wave = t >> 6;
    const int wr = wave >> 1, wc = wave & 1, m16 = lane & 15, quad = lane >> 4;
    const size_t rowBase = (size_t)blockIdx.y * 128 + wr * 64;
    const int colBase = blockIdx.x * 128 + wc * 64;
#pragma unroll
    for (int tm = 0; tm < 4; tm++)
#pragma unroll
        for (int tn = 0; tn < 4; tn++) {
            int col = colBase + tn * 16 + m16;
            float bv = bias[col];
#pragma unroll
            for (int r = 0; r < 4; r++) {
                size_t row = rowBase + tm * 16 + quad * 4 + r;
                out[row * 512 + col] = f2bf(acc[tm][tn][r] + bv);
            }
        }
}

// ---------------------------------------------------------------------------
// Fused scores + mask + softmax -> P (bf16). Grid (4, 512). K=64 (one iter).
// ---------------------------------------------------------------------------
__global__ __launch_bounds__(256) void k_attn_scores(const u16* __restrict__ qproj,
                                                     const u16* __restrict__ kproj,
                                                     const float* __restrict__ maskb,
                                                     u16* __restrict__ P)
{
    __shared__ __align__(16) u16 As[64 * 64];
    __shared__ __align__(16) u16 Bs[256 * 64];
    __shared__ float smax[64][5];
    __shared__ float ssum[64][5];
    const int rt = blockIdx.x;
    const int z = blockIdx.y;
    const int bg = z >> 4, h = z & 15, hbit = h >> 3, hlow = h & 7;
    const int b = bg & 15;
    const size_t base = (size_t)bg * 262144 + (size_t)hbit * 512 + (size_t)hlow * 64;
    const u16* A = qproj + base + (size_t)rt * 64 * 1024;
    const u16* B = kproj + base;
    f32x4 acc[4][4];
    gemm_tile<64, 256, 1, 4, 4, 4>(A, 1024, B, 1024, 64, As, Bs, acc);

    const int t = threadIdx.x, lane = t & 63, wc = t >> 6;
    const int m16 = lane & 15, quad = lane >> 4;

    float mb[4];
#pragma unroll
    for (int j = 0; j < 4; j++) mb[j] = maskb[b * 256 + wc * 64 + j * 16 + m16];
#pragma unroll
    for (int i = 0; i < 4; i++)
#pragma unroll
        for (int j = 0; j < 4; j++)
#pragma unroll
            for (int r = 0; r < 4; r++)
                acc[i][j][r] = acc[i][j][r] * 0.125f + mb[j];

#pragma unroll
    for (int i = 0; i < 4; i++)
#pragma unroll
        for (int r = 0; r < 4; r++) {
            float mm = fmaxf(fmaxf(acc[i][0][r], acc[i][1][r]), fmaxf(acc[i][2][r], acc[i][3][r]));
            mm = fmaxf(mm, __shfl_xor(mm, 1));
            mm = fmaxf(mm, __shfl_xor(mm, 2));
            mm = fmaxf(mm, __shfl_xor(mm, 4));
            mm = fmaxf(mm, __shfl_xor(mm, 8));
            if (m16 == 0) smax[i * 16 + quad * 4 + r][wc] = mm;
        }
    __syncthreads();
    float mrow[4][4];
#pragma unroll
    for (int i = 0; i < 4; i++)
#pragma unroll
        for (int r = 0; r < 4; r++) {
            int row = i * 16 + quad * 4 + r;
            mrow[i][r] = fmaxf(fmaxf(smax[row][0], smax[row][1]), fmaxf(smax[row][2], smax[row][3]));
        }
#pragma unroll
    for (int i = 0; i < 4; i++)
#pragma unroll
        for (int r = 0; r < 4; r++) {
            float s = 0.f;
#pragma unroll
            for (int j = 0; j < 4; j++) {
                float e = __expf(acc[i][j][r] - mrow[i][r]);
                acc[i][j][r] = e;
                s += e;
            }
            s += __shfl_xor(s, 1);
            s += __shfl_xor(s, 2);
            s += __shfl_xor(s, 4);
            s += __shfl_xor(s, 8);
            if (m16 == 0) ssum[i * 16 + quad * 4 + r][wc] = s;
        }
    __syncthreads();
    u16* out = P + (size_t)z * 65536 + (size_t)rt * 64 * 256;
#pragma unroll
    for (int i = 0; i < 4; i++)
#pragma unroll
        for (int r = 0; r < 4; r++) {
            int row = i * 16 + quad * 4 + r;
            float inv = 1.0f / (ssum[row][0] + ssum[row][1] + ssum[row][2] + ssum[row][3]);
#pragma unroll
            for (int j = 0; j < 4; j++) {
                int col = wc * 64 + j * 16 + m16;
                out[(size_t)row * 256 + col] = f2bf(acc[i][j][r] * inv);
            }
        }
}

// vT[(bg*16+h)*64 + dh][s] = vproj[bg][l=2s+hbit][hlow*64+dh]
__global__ __launch_bounds__(256) void k_transpose_v(const u16* __restrict__ vproj, u16* __restrict__ vT)
{
    __shared__ __align__(16) u16 tile[64 * 72];
    const int lt = blockIdx.x, hlow = blockIdx.y, bg = blockIdx.z;
    const int t = threadIdx.x;
    {
        int rl = t >> 2, c16 = (t & 3) * 16;
        const u16* src = vproj + (size_t)bg * 262144 + (size_t)(lt * 64 + rl) * 512 + hlow * 64 + c16;
        *(us8*)(tile + rl * 72 + c16)     = *(const us8*)src;
        *(us8*)(tile + rl * 72 + c16 + 8) = *(const us8*)(src + 8);
    }
    __syncthreads();
    const int lanej = t & 31, grp = t >> 5;
#pragma unroll
    for (int hbit = 0; hbit < 2; hbit++) {
        int h = hbit * 8 + hlow;
#pragma unroll
        for (int i = 0; i < 8; i++) {
            int dh = grp + i * 8;
            u16 val = tile[(2 * lanej + hbit) * 72 + dh];
            vT[(((size_t)bg * 16 + h) * 64 + dh) * 256 + lt * 32 + lanej] = val;
        }
    }
}

// ctx = P V, scatter into attedpre (B,L,H). Grid (2, 512). K=256.
__global__ __launch_bounds__(256) void k_gemm_ctx(const u16* __restrict__ P,
                                                  const u16* __restrict__ vT,
                                                  u16* __restrict__ attedpre)
{
    __shared__ __align__(16) u16 As[128 * 64];
    __shared__ __align__(16) u16 Bs[64 * 64];
    const int z = blockIdx.y;
    const u16* A = P + (size_t)z * 65536 + (size_t)blockIdx.x * 128 * 256;
    const u16* B = vT + (size_t)z * 16384;
    f32x4 acc[2][4];
    gemm_tile<128, 64, 4, 1, 2, 4>(A, 256, B, 256, 256, As, Bs, acc);

    const int t = threadIdx.x, lane = t & 63, wave = t >> 6;
    const int m16 = lane & 15, quad = lane >> 4;
    const int bg = z >> 4, h = z & 15;
    const int g = bg >> 4, b = bg & 15, hbit = h >> 3, hlow = h & 7;
    const int cBase = g * 512 + hlow * 64;
#pragma unroll
    for (int tm = 0; tm < 2; tm++)
#pragma unroll
        for (int tn = 0; tn < 4; tn++) {
            int dh = tn * 16 + m16;
#pragma unroll
            for (int r = 0; r < 4; r++) {
                int s = blockIdx.x * 128 + wave * 32 + tm * 16 + quad * 4 + r;
                int l = 2 * s + hbit;
                attedpre[((size_t)b * 512 + l) * 1024 + cBase + dh] = f2bf(acc[tm][tn][r]);
            }
        }
}

// Fused grouped FFN2: grid (8, 64). x -> (g = x>>2, xn = x&3).
__global__ __launch_bounds__(256) void k_gemm_ffn2(const u16* __restrict__ h1,
                                                   const u16* __restrict__ W2T,
                                                   const float* __restrict__ b2,
                                                   u16* __restrict__ out)
{
    __shared__ __align__(16) u16 As[128 * 64];
    __shared__ __align__(16) u16 Bs[128 * 64];
    const int xi = blockIdx.x;
    const int g = xi >> 2, xn = xi & 3;
    const u16* Ab = h1 + (size_t)blockIdx.y * 128 * 4096 + g * 2048;
    const u16* Bb = W2T + (size_t)xn * 128 * 2048;
    f32x4 acc[4][4];
    gemm_tile<128, 128, 2, 2, 4, 4>(Ab, 4096, Bb, 2048, 2048, As, Bs, acc);

    const int t = threadIdx.x, lane = t & 63, wave = t >> 6;
    const int wr = wave >> 1, wc = wave & 1, m16 = lane & 15, quad = lane >> 4;
    const size_t rowBase = (size_t)blockIdx.y * 128 + wr * 64;
    const int colg = xn * 128 + wc * 64;
#pragma unroll
    for (int tm = 0; tm < 4; tm++)
#pragma unroll
        for (int tn = 0; tn < 4; tn++) {
            int cg = colg + tn * 16 + m16;
            float bv = b2[cg];
#pragma unroll
            for (int r = 0; r < 4; r++) {
                size_t row = rowBase + tm * 16 + quad * 4 + r;
                out[row * 1024 + g * 512 + cg] = f2bf(acc[tm][tn][r] + bv);
            }
        }
}

// out = LN(x1 + x2) * gamma + beta over D=1024; one block per row.
template<int FINAL>
__global__ __launch_bounds__(256) void k_ln(const u16* __restrict__ x1, const u16* __restrict__ x2,
                                            const float* __restrict__ gamma, const float* __restrict__ beta,
                                            void* __restrict__ outv, const int* __restrict__ yflag)
{
    const size_t row = blockIdx.x;
    const int t = threadIdx.x;
    us4 a = *(const us4*)(x1 + row * 1024 + t * 4);
    us4 b = *(const us4*)(x2 + row * 1024 + t * 4);
    float v[4]; float s = 0.f, s2 = 0.f;
#pragma unroll
    for (int i = 0; i < 4; i++) { v[i] = bf2f(a[i]) + bf2f(b[i]); s += v[i]; s2 += v[i] * v[i]; }
#pragma unroll
    for (int off = 32; off > 0; off >>= 1) { s += __shfl_xor(s, off); s2 += __shfl_xor(s2, off); }
    __shared__ float red[8];
    const int lane = t & 63, wave = t >> 6;
    if (lane == 0) { red[wave] = s; red[wave + 4] = s2; }
    __syncthreads();
    s = red[0] + red[1] + red[2] + red[3];
    s2 = red[4] + red[5] + red[6] + red[7];
    float mean = s * (1.0f / 1024.0f);
    float var = fmaxf(s2 * (1.0f / 1024.0f) - mean * mean, 0.0f);
    float rs = rsqrtf(var + 1e-6f);
    float o[4];
#pragma unroll
    for (int i = 0; i < 4; i++) {
        int c = t * 4 + i;
        o[i] = (v[i] - mean) * rs * gamma[c] + beta[c];
    }
    bool f32out = FINAL && yflag && (*yflag == 3);
    if (f32out) {
        float* out = (float*)outv;
#pragma unroll
        for (int i = 0; i < 4; i++) out[row * 1024 + t * 4 + i] = o[i];
    } else {
        u16* out = (u16*)outv;
        us4 ov;
#pragma unroll
        for (int i = 0; i < 4; i++) ov[i] = f2bf(o[i]);
        *(us4*)(out + row * 1024 + t * 4) = ov;
    }
}

// ---------------------------------------------------------------------------
extern "C" void kernel_launch(void* const* d_in, const int* in_sizes, int n_in,
                              void* d_out, int out_size, void* d_ws, size_t ws_size,
                              hipStream_t stream)
{
    (void)in_sizes; (void)n_in; (void)out_size; (void)ws_size;
    const void* y    = d_in[0];
    const void* mask = d_in[1];
    const void* Wv = d_in[2];  const void* bv = d_in[3];
    const void* Wk = d_in[4];  const void* bk = d_in[5];
    const void* Wq = d_in[6];  const void* bq = d_in[7];
    const void* Wm = d_in[8];  const void* bm = d_in[9];
    const void* W1 = d_in[10]; const void* b1 = d_in[11];
    const void* W2 = d_in[12]; const void* b2 = d_in[13];
    const void* g1 = d_in[14]; const void* be1 = d_in[15];
    const void* g2 = d_in[16]; const void* be2 = d_in[17];

    char* ws = (char*)d_ws;
    size_t off = 0;
    auto alloc = [&](size_t bytes) { void* p = ws + off; off = (off + bytes + 255) & ~(size_t)255; return p; };

    int*   flags = (int*)alloc(32 * 4);
    float* maskb = (float*)alloc(16 * 256 * 4);
    float* par   = (float*)alloc(11264 * 4);
    u16* WqT  = (u16*)alloc((size_t)262144 * 2);
    u16* WkT  = (u16*)alloc((size_t)262144 * 2);
    u16* WvT  = (u16*)alloc((size_t)262144 * 2);
    u16* WmT  = (u16*)alloc((size_t)1048576 * 2);
    u16* W1T  = (u16*)alloc((size_t)4194304 * 2);
    u16* W2T  = (u16*)alloc((size_t)1048576 * 2);
    u16* y_c  = (u16*)alloc((size_t)8388608 * 2);
    u16* slotA = (u16*)alloc((size_t)8388608 * 2);   // qproj -> mergeout
    u16* slotB = (u16*)alloc((size_t)8388608 * 2);   // kproj -> y1
    u16* slotC = (u16*)alloc((size_t)8388608 * 2);   // vT -> ffout
    u16* slotD = (u16*)alloc((size_t)8388608 * 2);   // vproj -> attedpre
    u16* Pbig  = (u16*)alloc((size_t)33554432 * 2);  // P (64 MB) -> h1 (32 MB)

    float* p_bm  = par + 1536;
    float* p_b1  = par + 2560;
    float* p_b2  = par + 6656;
    float* p_g1  = par + 7168;
    float* p_be1 = par + 8192;
    float* p_g2  = par + 9216;
    float* p_be2 = par + 10240;

    DetectArgs da;
    {
        const void* srcs[18] = {y, mask, Wv, bv, Wk, bk, Wq, bq, Wm, bm, W1, b1, W2, b2, g1, be1, g2, be2};
        const int   nele[18] = {8388608, 4096, 262144, 512, 262144, 512, 262144, 512, 1048576, 1024,
                                4194304, 4096, 1048576, 512, 1024, 1024, 1024, 1024};
        for (int i = 0; i < 18; i++) { da.p[i] = srcs[i]; da.nw[i] = nele[i] < 4096 ? nele[i] : 4096; }
    }
    k_detect_all<<<18, 256, 0, stream>>>(da, flags);

    k_expand_mask<<<16, 256, 0, stream>>>(mask, flags + 1, maskb);
    k_convert_bf<<<32768, 256, 0, stream>>>(y, y_c, 8388608, flags + 0);

    TransArgs ta;
    {
        const void* s6[6] = {Wq, Wk, Wv, Wm, W1, W2};
        u16* d6[6] = {WqT, WkT, WvT, WmT, W1T, W2T};
        int R6[6] = {512, 512, 512, 1024, 1024, 2048};
        int C6[6] = {512, 512, 512, 1024, 4096, 512};
        int f6[6] = {6, 4, 2, 8, 10, 12};
        int ts[7] = {0, 256, 512, 768, 1792, 5888, 6912};
        for (int i = 0; i < 6; i++) { ta.src[i] = s6[i]; ta.dst[i] = d6[i]; ta.R[i] = R6[i]; ta.C[i] = C6[i]; ta.flagidx[i] = f6[i]; }
        for (int i = 0; i < 7; i++) ta.tstart[i] = ts[i];
    }
    k_transpose_all<<<6912, 256, 0, stream>>>(ta, flags);

    ConvArgs ca;
    {
        const void* s10[10] = {bq, bk, bv, bm, b1, b2, g1, be1, g2, be2};
        int f10[10] = {7, 5, 3, 9, 11, 13, 14, 15, 16, 17};
        int o10[10] = {0, 512, 1024, 1536, 2560, 6656, 7168, 8192, 9216, 10240};
        int n10[10] = {512, 512, 512, 1024, 4096, 512, 1024, 1024, 1024, 1024};
        for (int i = 0; i < 10; i++) { ca.src[i] = s10[i]; ca.flagidx[i] = f10[i]; ca.off[i] = o10[i]; ca.n[i] = n10[i]; }
    }
    k_convert_params<<<44, 256, 0, stream>>>(ca, flags, par);

    u16* qproj = slotA;
    u16* kproj = slotB;
    u16* vT    = slotC;
    u16* vproj = slotD;

    k_gemm_qkv<<<dim3(4, 64, 6), 256, 0, stream>>>(y_c, WqT, WkT, WvT, par, qproj, kproj, vproj);
    k_transpose_v<<<dim3(8, 8, 32), 256, 0, stream>>>(vproj, vT);

    u16* P = Pbig;
    k_attn_scores<<<dim3(4, 512), 256, 0, stream>>>(qproj, kproj, maskb, P);

    u16* attedpre = slotD;   // vproj dead
    k_gemm_ctx<<<dim3(2, 512), 256, 0, stream>>>(P, vT, attedpre);

    u16* mergeout = slotA;   // qproj dead
    k_gemm_std<false><<<dim3(8, 64), 256, 0, stream>>>(attedpre, 1024, WmT, 1024, p_bm, mergeout, 1024, 1024);

    u16* y1 = slotB;         // kproj dead
    k_ln<0><<<8192, 256, 0, stream>>>(y_c, mergeout, p_g1, p_be1, y1, nullptr);

    u16* h1 = Pbig;          // P dead after ctx
    // A/B split: rows 0-4095 via the fixed 256^2 pipeline, rows 4096-8191
    // via the proven 128^2 core. rocprof times each dispatch separately.
    k_gemm256<true><<<dim3(16, 16), 512, 0, stream>>>(y1, 1024, W1T, 1024, p_b1, h1, 4096, 1024);
    k_gemm_std<true><<<dim3(32, 32), 256, 0, stream>>>(y1 + (size_t)4096 * 1024, 1024, W1T, 1024, p_b1,
                                                       h1 + (size_t)4096 * 4096, 4096, 1024);

    u16* ffout = slotC;      // vT dead
    k_gemm_ffn2<<<dim3(8, 64), 256, 0, stream>>>(h1, W2T, p_b2, ffout);

    k_ln<1><<<8192, 256, 0, stream>>>(y1, ffout, p_g2, p_be2, d_out, flags + 0);
}

// Round 3
// 423.763 us; speedup vs baseline: 1.1615x; 1.1483x over previous
//
#include <hip/hip_runtime.h>
#include <stdint.h>

typedef unsigned short u16;
using us8   = __attribute__((ext_vector_type(8))) unsigned short;
using us4   = __attribute__((ext_vector_type(4))) unsigned short;
using bf16x8 = __attribute__((ext_vector_type(8))) __bf16;
using f32x4 = __attribute__((ext_vector_type(4))) float;

#define DEV static __device__ __forceinline__

DEV float bf2f(u16 u) { union { uint32_t i; float f; } v; v.i = (uint32_t)u << 16; return v.f; }
DEV u16 f2bf(float f) {
    union { float f; uint32_t i; } v; v.f = f;
    uint32_t u = v.i;
    return (u16)((u + 0x7FFFu + ((u >> 16) & 1u)) >> 16);
}

// async global->LDS 16B copy: lane l writes LDS at (uniform base) + l*16B.
DEV void async16(const u16* g, u16* ldsbase)
{
    __builtin_amdgcn_global_load_lds((const __attribute__((address_space(1))) void*)g,
                                     (__attribute__((address_space(3))) void*)ldsbase, 16, 0, 0);
}

// ---------------------------------------------------------------------------
// Fused dtype detection: 18 blocks, one per input tensor.
// ---------------------------------------------------------------------------
struct DetectArgs { const void* p[18]; int nw[18]; };

__global__ __launch_bounds__(256) void k_detect_all(DetectArgs a, int* flags)
{
    const int b = blockIdx.x;
    const int t = threadIdx.x;
    __shared__ int cnt[4];
    if (t < 4) cnt[t] = 0;
    __syncthreads();
    if (b == 1) {
        const uint8_t* m = (const uint8_t*)a.p[1];
        int c0 = 0, c1 = 0, c2 = 0, c3 = 0;
        for (int i = t; i < 4096; i += 256) {
            uint8_t v = m[i];
            int mod = i & 3;
            if (v == 0x3F && mod == 1) c0++;
            if (v == 0x3F && mod == 3) c1++;
            if (v == 1 && mod != 0) c2++;
            if (v == 1 && mod == 0) c3++;
        }
        atomicAdd(&cnt[0], c0); atomicAdd(&cnt[1], c1); atomicAdd(&cnt[2], c2); atomicAdd(&cnt[3], c3);
        __syncthreads();
        if (t == 0) {
            int mf;
            if (cnt[0] > 0) mf = 2;
            else if (cnt[1] > 0) mf = 3;
            else if (cnt[2] > 0) mf = 0;
            else if (cnt[3] > 0) mf = 1;
            else mf = 0;
            flags[1] = mf;
        }
    } else {
        const u16* p = (const u16*)a.p[b];
        int nw = a.nw[b];
        int nze = 0, pe = 0, nzo = 0;
        for (int i = t; i < nw; i += 256) {
            u16 w = p[i];
            if (w == 0) continue;
            int e = (w >> 7) & 0xFF;
            bool pl = (e >= 90 && e <= 140);
            if ((i & 1) == 0) { nze++; if (pl) pe++; }
            else nzo++;
        }
        atomicAdd(&cnt[0], nze); atomicAdd(&cnt[1], pe); atomicAdd(&cnt[2], nzo);
        __syncthreads();
        if (t == 0) {
            int f;
            if (cnt[0] > 0)      f = (cnt[1] * 10 >= cnt[0] * 6) ? 2 : 3;
            else if (cnt[2] > 0) f = 3;
            else                 f = 2;
            flags[b] = f;
        }
    }
}

__global__ __launch_bounds__(256) void k_expand_mask(const void* mask, const int* flag, float* mb)
{
    int i = blockIdx.x * 256 + threadIdx.x;
    if (i >= 4096) return;
    int f = *flag;
    bool on;
    if (f == 0)      on = ((const uint8_t*)mask)[i]  != 0;
    else if (f == 1) on = ((const int*)mask)[i]      != 0;
    else if (f == 2) on = ((const u16*)mask)[i]      != 0;
    else             on = ((const uint32_t*)mask)[i] != 0;
    mb[i] = on ? -1e9f : 0.0f;
}

__global__ __launch_bounds__(256) void k_convert_bf(const void* src, u16* dst, int n, const int* flag)
{
    int i = blockIdx.x * 256 + threadIdx.x;
    if (i >= n) return;
    if (*flag == 2) dst[i] = ((const u16*)src)[i];
    else            dst[i] = f2bf(((const float*)src)[i]);
}

// ---------------------------------------------------------------------------
// Fused LDS-tiled weight transposes
// ---------------------------------------------------------------------------
struct TransArgs { const void* src[6]; u16* dst[6]; int R[6]; int C[6]; int flagidx[6]; int tstart[7]; };

__global__ __launch_bounds__(256) void k_transpose_all(TransArgs a, const int* flags)
{
    const int tb = blockIdx.x;
    int s = 0;
    while (tb >= a.tstart[s + 1]) s++;
    const int lt = tb - a.tstart[s];
    const int R = a.R[s], C = a.C[s];
    const int tilesX = C >> 5;
    const int ti = lt / tilesX, tj = lt - ti * tilesX;
    const int r0 = ti * 32, c0 = tj * 32;
    const bool isbf = (flags[a.flagidx[s]] == 2);
    const int t = threadIdx.x;
    const int j = t & 31, i0 = t >> 5;
    __shared__ u16 tile[32][33];
#pragma unroll
    for (int p = 0; p < 4; p++) {
        int r = r0 + i0 + p * 8;
        size_t idx = (size_t)r * C + c0 + j;
        u16 v = isbf ? ((const u16*)a.src[s])[idx] : f2bf(((const float*)a.src[s])[idx]);
        tile[i0 + p * 8][j] = v;
    }
    __syncthreads();
    u16* dst = a.dst[s];
#pragma unroll
    for (int p = 0; p < 4; p++) {
        int c = i0 + p * 8;
        dst[(size_t)(c0 + c) * R + r0 + j] = tile[j][c];
    }
}

// ---------------------------------------------------------------------------
// Fused param converts
// ---------------------------------------------------------------------------
struct ConvArgs { const void* src[10]; int flagidx[10]; int off[10]; int n[10]; };

__global__ __launch_bounds__(256) void k_convert_params(ConvArgs a, const int* flags, float* par)
{
    int i = blockIdx.x * 256 + threadIdx.x;
    if (i >= 11264) return;
    int s = 0;
    while (s < 9 && i >= a.off[s] + a.n[s]) s++;
    int j = i - a.off[s];
    float v;
    if (flags[a.flagidx[s]] == 2) v = bf2f(((const u16*)a.src[s])[j]);
    else                          v = ((const float*)a.src[s])[j];
    par[i] = v;
}

// ---------------------------------------------------------------------------
// MFMA GEMM core, BK=64, async global->LDS staging with XOR-swizzled layout.
// C(M x N) = A(M x K, lda) * Bt(N x K, ldb)^T. fp32 accum. 256 threads.
// LDS tile: BM(/BN) rows x 64 cols bf16, rows stride 64 el (128 B), row r's
// 8-col chunk j stored at slot j^(r&7)  ->  fragment ds_read_b128 hits all 32
// banks with 2 lanes/bank (free).  Staged in 1 KB chunks of 8 rows: lane l
// loads row chunk*8 + l/8, col-chunk (l&7)^(l>>3).
// K must be a multiple of 64. BM, BN multiples of 32.
// ---------------------------------------------------------------------------
template<int BM, int BN, int WR, int WC, int TM, int TN>
DEV void gemm_tile(const u16* __restrict__ A, int lda,
                   const u16* __restrict__ Bt, int ldb, int K,
                   u16* As, u16* Bs, f32x4 (&acc)[TM][TN])
{
    const int t = threadIdx.x;
    const int lane = t & 63;
    const int wave = t >> 6;
    const int wr = wave / WC;
    const int wc = wave % WC;
    const int m16 = lane & 15;
    const int quad = lane >> 4;
    const int lr8 = lane >> 3;                 // 0..7 row within 8-row chunk
    const int lsw = (((lane & 7) ^ lr8) << 3); // swizzled col offset (elements)

#pragma unroll
    for (int i = 0; i < TM; i++)
#pragma unroll
        for (int j = 0; j < TN; j++) {
            acc[i][j][0] = 0.f; acc[i][j][1] = 0.f; acc[i][j][2] = 0.f; acc[i][j][3] = 0.f;
        }

    for (int kb = 0; kb < K; kb += 64) {
#pragma unroll
        for (int i = 0; i < BM / 32; i++) {
            int chunk = wave * (BM / 32) + i;
            int r = chunk * 8 + lr8;
            async16(A + (size_t)r * lda + kb + lsw, As + chunk * 512);
        }
#pragma unroll
        for (int i = 0; i < BN / 32; i++) {
            int chunk = wave * (BN / 32) + i;
            int r = chunk * 8 + lr8;
            async16(Bt + (size_t)r * ldb + kb + lsw, Bs + chunk * 512);
        }
        __syncthreads();   // drains vmcnt (incl. global_load_lds) before LDS reads
#pragma unroll
        for (int ks = 0; ks < 2; ks++) {
            bf16x8 af[TM], bfr[TN];
#pragma unroll
            for (int i = 0; i < TM; i++) {
                int row = wr * TM * 16 + i * 16 + m16;
                int jq = ks * 4 + quad;
                af[i] = *(const bf16x8*)(As + row * 64 + ((jq ^ (row & 7)) << 3));
            }
#pragma unroll
            for (int j = 0; j < TN; j++) {
                int row = wc * TN * 16 + j * 16 + m16;
                int jq = ks * 4 + quad;
                bfr[j] = *(const bf16x8*)(Bs + row * 64 + ((jq ^ (row & 7)) << 3));
            }
#pragma unroll
            for (int i = 0; i < TM; i++)
#pragma unroll
                for (int j = 0; j < TN; j++)
                    acc[i][j] = __builtin_amdgcn_mfma_f32_16x16x32_bf16(af[i], bfr[j], acc[i][j], 0, 0, 0);
        }
        __syncthreads();
    }
}

template<bool RELU>
__global__ __launch_bounds__(256) void k_gemm_std(const u16* __restrict__ A, int lda,
                                                  const u16* __restrict__ Bt, int ldb,
                                                  const float* __restrict__ bias,
                                                  u16* __restrict__ C, int ldc, int K)
{
    __shared__ __align__(16) u16 As[128 * 64];
    __shared__ __align__(16) u16 Bs[128 * 64];
    const u16* Ab = A + (size_t)blockIdx.y * 128 * lda;
    const u16* Bb = Bt + (size_t)blockIdx.x * 128 * ldb;
    f32x4 acc[4][4];
    gemm_tile<128, 128, 2, 2, 4, 4>(Ab, lda, Bb, ldb, K, As, Bs, acc);

    const int t = threadIdx.x, lane = t & 63, wave = t >> 6;
    const int wr = wave >> 1, wc = wave & 1, m16 = lane & 15, quad = lane >> 4;
    const size_t rowBase = (size_t)blockIdx.y * 128 + wr * 64;
    const int colBase = blockIdx.x * 128 + wc * 64;
#pragma unroll
    for (int tm = 0; tm < 4; tm++)
#pragma unroll
        for (int tn = 0; tn < 4; tn++) {
            int col = colBase + tn * 16 + m16;
            float bv = bias ? bias[col] : 0.f;
#pragma unroll
            for (int r = 0; r < 4; r++) {
                size_t row = rowBase + tm * 16 + quad * 4 + r;
                float v = acc[tm][tn][r] + bv;
                if (RELU) v = fmaxf(v, 0.f);
                C[row * (size_t)ldc + col] = f2bf(v);
            }
        }
}

// Fused QKV: grid (4, 64, 6); z -> (g = z/3, mat = z%3). M=8192 N=512 K=512.
__global__ __launch_bounds__(256) void k_gemm_qkv(const u16* __restrict__ y_c,
                                                  const u16* __restrict__ WqT,
                                                  const u16* __restrict__ WkT,
                                                  const u16* __restrict__ WvT,
                                                  const float* __restrict__ biases,
                                                  u16* __restrict__ qp, u16* __restrict__ kp, u16* __restrict__ vp)
{
    __shared__ __align__(16) u16 As[128 * 64];
    __shared__ __align__(16) u16 Bs[128 * 64];
    const int z = blockIdx.z;
    const int mat = z % 3, g = z / 3;
    const u16* Bt = (mat == 0) ? WqT : (mat == 1) ? WkT : WvT;
    u16* out = ((mat == 0) ? qp : (mat == 1) ? kp : vp) + (size_t)g * 4194304;
    const float* bias = biases + mat * 512;
    const u16* Ab = y_c + g * 512 + (size_t)blockIdx.y * 128 * 1024;
    const u16* Bb = Bt + (size_t)blockIdx.x * 128 * 512;
    f32x4 acc[4][4];
    gemm_tile<128, 128, 2, 2, 4, 4>(Ab, 1024, Bb, 512, 512, As, Bs, acc);

    const int t = threadIdx.x, lane = t & 63, wave = t >> 6;
    const int wr = wave >> 1, wc = wave & 1, m16 = lane & 15, quad = lane >> 4;
    const size_t rowBase = (size_t)blockIdx.y * 128 + wr * 64;
    const int colBase = blockIdx.x * 128 + wc * 64;
#pragma unroll
    for (int tm = 0; tm < 4; tm++)
#pragma unroll
        for (int tn = 0; tn < 4; tn++) {
            int col = colBase + tn * 16 + m16;
            float bv = bias[col];
#pragma unroll
            for (int r = 0; r < 4; r++) {
                size_t row = rowBase + tm * 16 + quad * 4 + r;
                out[row * 512 + col] = f2bf(acc[tm][tn][r] + bv);
            }
        }
}

// vT[(bg*16+h)*64 + dh][s] = vproj[bg][l=2s+hbit][hlow*64+dh]
__global__ __launch_bounds__(256) void k_transpose_v(const u16* __restrict__ vproj, u16* __restrict__ vT)
{
    __shared__ __align__(16) u16 tile[64 * 72];
    const int lt = blockIdx.x, hlow = blockIdx.y, bg = blockIdx.z;
    const int t = threadIdx.x;
    {
        int rl = t >> 2, c16 = (t & 3) * 16;
        const u16* src = vproj + (size_t)bg * 262144 + (size_t)(lt * 64 + rl) * 512 + hlow * 64 + c16;
        *(us8*)(tile + rl * 72 + c16)     = *(const us8*)src;
        *(us8*)(tile + rl * 72 + c16 + 8) = *(const us8*)(src + 8);
    }
    __syncthreads();
    const int lanej = t & 31, grp = t >> 5;
#pragma unroll
    for (int hbit = 0; hbit < 2; hbit++) {
        int h = hbit * 8 + hlow;
#pragma unroll
        for (int i = 0; i < 8; i++) {
            int dh = grp + i * 8;
            u16 val = tile[(2 * lanej + hbit) * 72 + dh];
            vT[(((size_t)bg * 16 + h) * 64 + dh) * 256 + lt * 32 + lanej] = val;
        }
    }
}

// ---------------------------------------------------------------------------
// Fused flash-style attention: scores + mask + softmax + P*V in ONE kernel.
// Grid 512 (one block per z = bg*16+h), 512 threads = 8 waves. Each wave owns
// 32 q-rows end to end. Replaces k_attn_scores (74 us, MfmaUtil 2%) +
// k_gemm_ctx, and removes the 64 MB P write + 64 MB P read.
//   LDS: Ks 256x64 (32 KB, gemm swizzle), Vs=vT tile 64x256 (32 KB, low-3
//   XOR swizzle per 16B chunk), Ps per-wave 32x64 P-chunk dbuf (64 KB).
//   S acc[2][16] in regs; softmax fully in-wave (16-lane shfl_xor);
//   P routed C-layout -> A-layout through the 4 KB per-wave LDS chunk.
// ---------------------------------------------------------------------------
__global__ __launch_bounds__(512, 2) void k_attn_fused(const u16* __restrict__ qproj,
                                                       const u16* __restrict__ kproj,
                                                       const u16* __restrict__ vT,
                                                       const float* __restrict__ maskb,
                                                       u16* __restrict__ attedpre)
{
    __shared__ __align__(16) u16 Ks[256 * 64];      // 32 KB
    __shared__ __align__(16) u16 Vs[64 * 256];      // 32 KB
    __shared__ __align__(16) u16 Ps[8 * 2 * 2048];  // 64 KB: per-wave dbuf P chunks

    const int z = blockIdx.x;
    const int bg = z >> 4, h = z & 15, hbit = h >> 3, hlow = h & 7;
    const int b = bg & 15, g = bg >> 4;
    const int t = threadIdx.x, lane = t & 63, wave = t >> 6;
    const int m16 = lane & 15, quad = lane >> 4;
    const int lr8 = lane >> 3;
    const int lsw = (((lane & 7) ^ lr8) << 3);

    const size_t base = (size_t)bg * 262144 + (size_t)hbit * 512 + (size_t)hlow * 64;
    const u16* Qb = qproj + base;
    const u16* Kb = kproj + base;

    // ---- stage K (256 rows x 64 cols, row stride 1024): 32 chunks of 8 rows ----
#pragma unroll
    for (int i = 0; i < 4; i++) {
        int chunk = wave * 4 + i;
        int row = chunk * 8 + lr8;
        async16(Kb + (size_t)row * 1024 + lsw, Ks + chunk * 512);
    }
    // ---- stage V^T (64 rows x 256 cols contiguous): 32 chunks of 2 rows ----
    // elem (d, 8-chunk j) lands at slot (j&24)|((j&7)^(d&7)) of row d: pre-swizzle
    // the per-lane global source so the linear LDS write gives the swizzled layout.
    const u16* Vb = vT + (size_t)z * 16384;
#pragma unroll
    for (int i = 0; i < 4; i++) {
        int chunk = wave * 4 + i;
        int d = chunk * 2 + (lane >> 5);
        int jl = lane & 31;
        int jsrc = (jl & 24) | ((jl & 7) ^ (d & 7));
        async16(Vb + (size_t)d * 256 + jsrc * 8, Vs + chunk * 512);
    }

    // ---- Q A-frags direct from global (independent of the staging above) ----
    bf16x8 qf[2][2];  // [mtile][ks]
#pragma unroll
    for (int mt = 0; mt < 2; mt++)
#pragma unroll
        for (int ks = 0; ks < 2; ks++) {
            int qrow = wave * 32 + mt * 16 + m16;
            qf[mt][ks] = *(const bf16x8*)(Qb + (size_t)qrow * 1024 + ks * 32 + quad * 8);
        }
    // ---- mask values (per s-column; col = nt*16 + m16) ----
    float mb[16];
#pragma unroll
    for (int nt = 0; nt < 16; nt++) mb[nt] = maskb[b * 256 + nt * 16 + m16];

    __syncthreads();   // K, V staged (drains vmcnt)

    // ---- S = Q K^T : acc[mt][nt], q-row = mt*16+quad*4+r, s-col = nt*16+(lane&15) ----
    f32x4 s[2][16];
#pragma unroll
    for (int mt = 0; mt < 2; mt++)
#pragma unroll
        for (int nt = 0; nt < 16; nt++) { s[mt][nt][0] = 0.f; s[mt][nt][1] = 0.f; s[mt][nt][2] = 0.f; s[mt][nt][3] = 0.f; }
#pragma unroll
    for (int ks = 0; ks < 2; ks++) {
        int jq = ks * 4 + quad;
#pragma unroll
        for (int nt = 0; nt < 16; nt++) {
            int row = nt * 16 + m16;
            bf16x8 kf = *(const bf16x8*)(Ks + row * 64 + ((jq ^ (row & 7)) << 3));
#pragma unroll
            for (int mt = 0; mt < 2; mt++)
                s[mt][nt] = __builtin_amdgcn_mfma_f32_16x16x32_bf16(qf[mt][ks], kf, s[mt][nt], 0, 0, 0);
        }
    }

    // ---- softmax, fully in-wave (rows live on (quad, r); cols on lane&15 x nt) ----
    float rinv[2][4];
#pragma unroll
    for (int mt = 0; mt < 2; mt++)
#pragma unroll
        for (int r = 0; r < 4; r++) {
            float mm = -3.0e38f;
#pragma unroll
            for (int nt = 0; nt < 16; nt++) {
                float v = s[mt][nt][r] * 0.125f + mb[nt];
                s[mt][nt][r] = v;
                mm = fmaxf(mm, v);
            }
            mm = fmaxf(mm, __shfl_xor(mm, 1));
            mm = fmaxf(mm, __shfl_xor(mm, 2));
            mm = fmaxf(mm, __shfl_xor(mm, 4));
            mm = fmaxf(mm, __shfl_xor(mm, 8));
            float ss = 0.f;
#pragma unroll
            for (int nt = 0; nt < 16; nt++) {
                float e = __expf(s[mt][nt][r] - mm);
                s[mt][nt][r] = e;
                ss += e;
            }
            ss += __shfl_xor(ss, 1);
            ss += __shfl_xor(ss, 2);
            ss += __shfl_xor(ss, 4);
            ss += __shfl_xor(ss, 8);
            rinv[mt][r] = 1.0f / ss;
        }

    // ---- ctx = P V : per 64-col P chunk, route C-layout -> A-layout via LDS ----
    f32x4 ctx[2][4];  // [mtile][dtile]
#pragma unroll
    for (int mt = 0; mt < 2; mt++)
#pragma unroll
        for (int dt = 0; dt < 4; dt++) { ctx[mt][dt][0] = 0.f; ctx[mt][dt][1] = 0.f; ctx[mt][dt][2] = 0.f; ctx[mt][dt][3] = 0.f; }

#pragma unroll
    for (int kc = 0; kc < 4; kc++) {
        u16* Pb = Ps + wave * 4096 + (kc & 1) * 2048;
        // write P chunk (32 rows x 64 cols), swizzled: elem (row,col) at
        // row*64 + ((j^(row&7))<<3)+e, j=col>>3, e=col&7
#pragma unroll
        for (int mt = 0; mt < 2; mt++)
#pragma unroll
            for (int nl = 0; nl < 4; nl++) {
                int nt = kc * 4 + nl;
#pragma unroll
                for (int r = 0; r < 4; r++) {
                    int row = mt * 16 + quad * 4 + r;
                    int col = nl * 16 + m16;
                    int j = col >> 3, e = col & 7;
                    Pb[row * 64 + (((j ^ (row & 7)) << 3) | e)] = f2bf(s[mt][nt][r] * rinv[mt][r]);
                }
            }
        // read back as A-frags and multiply with V
#pragma unroll
        for (int ks = 0; ks < 2; ks++) {
            int jq = ks * 4 + quad;
            bf16x8 pf[2];
#pragma unroll
            for (int mt = 0; mt < 2; mt++) {
                int row = mt * 16 + m16;
                pf[mt] = *(const bf16x8*)(Pb + row * 64 + ((jq ^ (row & 7)) << 3));
            }
#pragma unroll
            for (int dt = 0; dt < 4; dt++) {
                int d = dt * 16 + m16;
                int j = kc * 8 + ks * 4 + quad;
                int slot = (j & 24) | ((j & 7) ^ (d & 7));
                bf16x8 vf = *(const bf16x8*)(Vs + d * 256 + slot * 8);
#pragma unroll
                for (int mt = 0; mt < 2; mt++)
                    ctx[mt][dt] = __builtin_amdgcn_mfma_f32_16x16x32_bf16(pf[mt], vf, ctx[mt][dt], 0, 0, 0);
            }
        }
    }

    // ---- scatter ctx into attedpre (B,L,H): l = 2s+hbit, col = g*512+hlow*64+dh ----
    const int cBase = g * 512 + hlow * 64;
#pragma unroll
    for (int mt = 0; mt < 2; mt++)
#pragma unroll
        for (int dt = 0; dt < 4; dt++) {
            int dh = dt * 16 + m16;
#pragma unroll
            for (int r = 0; r < 4; r++) {
                int sI = wave * 32 + mt * 16 + quad * 4 + r;
                int l = 2 * sI + hbit;
                attedpre[((size_t)b * 512 + l) * 1024 + cBase + dh] = f2bf(ctx[mt][dt][r]);
            }
        }
}

// Fused grouped FFN2: grid (8, 64). x -> (g = x>>2, xn = x&3).
__global__ __launch_bounds__(256) void k_gemm_ffn2(const u16* __restrict__ h1,
                                                   const u16* __restrict__ W2T,
                                                   const float* __restrict__ b2,
                                                   u16* __restrict__ out)
{
    __shared__ __align__(16) u16 As[128 * 64];
    __shared__ __align__(16) u16 Bs[128 * 64];
    const int xi = blockIdx.x;
    const int g = xi >> 2, xn = xi & 3;
    const u16* Ab = h1 + (size_t)blockIdx.y * 128 * 4096 + g * 2048;
    const u16* Bb = W2T + (size_t)xn * 128 * 2048;
    f32x4 acc[4][4];
    gemm_tile<128, 128, 2, 2, 4, 4>(Ab, 4096, Bb, 2048, 2048, As, Bs, acc);

    const int t = threadIdx.x, lane = t & 63, wave = t >> 6;
    const int wr = wave >> 1, wc = wave & 1, m16 = lane & 15, quad = lane >> 4;
    const size_t rowBase = (size_t)blockIdx.y * 128 + wr * 64;
    const int colg = xn * 128 + wc * 64;
#pragma unroll
    for (int tm = 0; tm < 4; tm++)
#pragma unroll
        for (int tn = 0; tn < 4; tn++) {
            int cg = colg + tn * 16 + m16;
            float bv = b2[cg];
#pragma unroll
            for (int r = 0; r < 4; r++) {
                size_t row = rowBase + tm * 16 + quad * 4 + r;
                out[row * 1024 + g * 512 + cg] = f2bf(acc[tm][tn][r] + bv);
            }
        }
}

// out = LN(x1 + x2) * gamma + beta over D=1024; one block per row.
template<int FINAL>
__global__ __launch_bounds__(256) void k_ln(const u16* __restrict__ x1, const u16* __restrict__ x2,
                                            const float* __restrict__ gamma, const float* __restrict__ beta,
                                            void* __restrict__ outv, const int* __restrict__ yflag)
{
    const size_t row = blockIdx.x;
    const int t = threadIdx.x;
    us4 a = *(const us4*)(x1 + row * 1024 + t * 4);
    us4 b = *(const us4*)(x2 + row * 1024 + t * 4);
    float v[4]; float s = 0.f, s2 = 0.f;
#pragma unroll
    for (int i = 0; i < 4; i++) { v[i] = bf2f(a[i]) + bf2f(b[i]); s += v[i]; s2 += v[i] * v[i]; }
#pragma unroll
    for (int off = 32; off > 0; off >>= 1) { s += __shfl_xor(s, off); s2 += __shfl_xor(s2, off); }
    __shared__ float red[8];
    const int lane = t & 63, wave = t >> 6;
    if (lane == 0) { red[wave] = s; red[wave + 4] = s2; }
    __syncthreads();
    s = red[0] + red[1] + red[2] + red[3];
    s2 = red[4] + red[5] + red[6] + red[7];
    float mean = s * (1.0f / 1024.0f);
    float var = fmaxf(s2 * (1.0f / 1024.0f) - mean * mean, 0.0f);
    float rs = rsqrtf(var + 1e-6f);
    float o[4];
#pragma unroll
    for (int i = 0; i < 4; i++) {
        int c = t * 4 + i;
        o[i] = (v[i] - mean) * rs * gamma[c] + beta[c];
    }
    bool f32out = FINAL && yflag && (*yflag == 3);
    if (f32out) {
        float* out = (float*)outv;
#pragma unroll
        for (int i = 0; i < 4; i++) out[row * 1024 + t * 4 + i] = o[i];
    } else {
        u16* out = (u16*)outv;
        us4 ov;
#pragma unroll
        for (int i = 0; i < 4; i++) ov[i] = f2bf(o[i]);
        *(us4*)(out + row * 1024 + t * 4) = ov;
    }
}

// ---------------------------------------------------------------------------
extern "C" void kernel_launch(void* const* d_in, const int* in_sizes, int n_in,
                              void* d_out, int out_size, void* d_ws, size_t ws_size,
                              hipStream_t stream)
{
    (void)in_sizes; (void)n_in; (void)out_size; (void)ws_size;
    const void* y    = d_in[0];
    const void* mask = d_in[1];
    const void* Wv = d_in[2];  const void* bv = d_in[3];
    const void* Wk = d_in[4];  const void* bk = d_in[5];
    const void* Wq = d_in[6];  const void* bq = d_in[7];
    const void* Wm = d_in[8];  const void* bm = d_in[9];
    const void* W1 = d_in[10]; const void* b1 = d_in[11];
    const void* W2 = d_in[12]; const void* b2 = d_in[13];
    const void* g1 = d_in[14]; const void* be1 = d_in[15];
    const void* g2 = d_in[16]; const void* be2 = d_in[17];

    char* ws = (char*)d_ws;
    size_t off = 0;
    auto alloc = [&](size_t bytes) { void* p = ws + off; off = (off + bytes + 255) & ~(size_t)255; return p; };

    int*   flags = (int*)alloc(32 * 4);
    float* maskb = (float*)alloc(16 * 256 * 4);
    float* par   = (float*)alloc(11264 * 4);
    u16* WqT  = (u16*)alloc((size_t)262144 * 2);
    u16* WkT  = (u16*)alloc((size_t)262144 * 2);
    u16* WvT  = (u16*)alloc((size_t)262144 * 2);
    u16* WmT  = (u16*)alloc((size_t)1048576 * 2);
    u16* W1T  = (u16*)alloc((size_t)4194304 * 2);
    u16* W2T  = (u16*)alloc((size_t)1048576 * 2);
    u16* y_c  = (u16*)alloc((size_t)8388608 * 2);
    u16* slotA = (u16*)alloc((size_t)8388608 * 2);   // qproj -> mergeout
    u16* slotB = (u16*)alloc((size_t)8388608 * 2);   // kproj -> y1
    u16* slotC = (u16*)alloc((size_t)8388608 * 2);   // vT -> ffout
    u16* slotD = (u16*)alloc((size_t)8388608 * 2);   // vproj -> attedpre
    u16* Pbig  = (u16*)alloc((size_t)33554432 * 2);  // h1 (32 MB)

    float* p_bm  = par + 1536;
    float* p_b1  = par + 2560;
    float* p_b2  = par + 6656;
    float* p_g1  = par + 7168;
    float* p_be1 = par + 8192;
    float* p_g2  = par + 9216;
    float* p_be2 = par + 10240;

    DetectArgs da;
    {
        const void* srcs[18] = {y, mask, Wv, bv, Wk, bk, Wq, bq, Wm, bm, W1, b1, W2, b2, g1, be1, g2, be2};
        const int   nele[18] = {8388608, 4096, 262144, 512, 262144, 512, 262144, 512, 1048576, 1024,
                                4194304, 4096, 1048576, 512, 1024, 1024, 1024, 1024};
        for (int i = 0; i < 18; i++) { da.p[i] = srcs[i]; da.nw[i] = nele[i] < 4096 ? nele[i] : 4096; }
    }
    k_detect_all<<<18, 256, 0, stream>>>(da, flags);

    k_expand_mask<<<16, 256, 0, stream>>>(mask, flags + 1, maskb);
    k_convert_bf<<<32768, 256, 0, stream>>>(y, y_c, 8388608, flags + 0);

    TransArgs ta;
    {
        const void* s6[6] = {Wq, Wk, Wv, Wm, W1, W2};
        u16* d6[6] = {WqT, WkT, WvT, WmT, W1T, W2T};
        int R6[6] = {512, 512, 512, 1024, 1024, 2048};
        int C6[6] = {512, 512, 512, 1024, 4096, 512};
        int f6[6] = {6, 4, 2, 8, 10, 12};
        int ts[7] = {0, 256, 512, 768, 1792, 5888, 6912};
        for (int i = 0; i < 6; i++) { ta.src[i] = s6[i]; ta.dst[i] = d6[i]; ta.R[i] = R6[i]; ta.C[i] = C6[i]; ta.flagidx[i] = f6[i]; }
        for (int i = 0; i < 7; i++) ta.tstart[i] = ts[i];
    }
    k_transpose_all<<<6912, 256, 0, stream>>>(ta, flags);

    ConvArgs ca;
    {
        const void* s10[10] = {bq, bk, bv, bm, b1, b2, g1, be1, g2, be2};
        int f10[10] = {7, 5, 3, 9, 11, 13, 14, 15, 16, 17};
        int o10[10] = {0, 512, 1024, 1536, 2560, 6656, 7168, 8192, 9216, 10240};
        int n10[10] = {512, 512, 512, 1024, 4096, 512, 1024, 1024, 1024, 1024};
        for (int i = 0; i < 10; i++) { ca.src[i] = s10[i]; ca.flagidx[i] = f10[i]; ca.off[i] = o10[i]; ca.n[i] = n10[i]; }
    }
    k_convert_params<<<44, 256, 0, stream>>>(ca, flags, par);

    u16* qproj = slotA;
    u16* kproj = slotB;
    u16* vT    = slotC;
    u16* vproj = slotD;

    k_gemm_qkv<<<dim3(4, 64, 6), 256, 0, stream>>>(y_c, WqT, WkT, WvT, par, qproj, kproj, vproj);
    k_transpose_v<<<dim3(8, 8, 32), 256, 0, stream>>>(vproj, vT);

    u16* attedpre = slotD;   // vproj dead after transpose_v
    k_attn_fused<<<512, 512, 0, stream>>>(qproj, kproj, vT, maskb, attedpre);

    u16* mergeout = slotA;   // qproj dead
    k_gemm_std<false><<<dim3(8, 64), 256, 0, stream>>>(attedpre, 1024, WmT, 1024, p_bm, mergeout, 1024, 1024);

    u16* y1 = slotB;         // kproj dead
    k_ln<0><<<8192, 256, 0, stream>>>(y_c, mergeout, p_g1, p_be1, y1, nullptr);

    u16* h1 = Pbig;
    k_gemm_std<true><<<dim3(32, 64), 256, 0, stream>>>(y1, 1024, W1T, 1024, p_b1, h1, 4096, 1024);

    u16* ffout = slotC;      // vT dead
    k_gemm_ffn2<<<dim3(8, 64), 256, 0, stream>>>(h1, W2T, p_b2, ffout);

    k_ln<1><<<8192, 256, 0, stream>>>(y1, ffout, p_g2, p_be2, d_out, flags + 0);
}

// Round 5
// 415.402 us; speedup vs baseline: 1.1849x; 1.0201x over previous
//
#include <hip/hip_runtime.h>
#include <stdint.h>

typedef unsigned short u16;
using us8   = __attribute__((ext_vector_type(8))) unsigned short;
using us4   = __attribute__((ext_vector_type(4))) unsigned short;
using bf16x8 = __attribute__((ext_vector_type(8))) __bf16;
using f32x4 = __attribute__((ext_vector_type(4))) float;

#define DEV static __device__ __forceinline__

DEV float bf2f(u16 u) { union { uint32_t i; float f; } v; v.i = (uint32_t)u << 16; return v.f; }
DEV u16 f2bf(float f) {
    union { float f; uint32_t i; } v; v.f = f;
    uint32_t u = v.i;
    return (u16)((u + 0x7FFFu + ((u >> 16) & 1u)) >> 16);
}

// async global->LDS 16B copy: lane l writes LDS at (uniform base) + l*16B.
DEV void async16(const u16* g, u16* ldsbase)
{
    __builtin_amdgcn_global_load_lds((const __attribute__((address_space(1))) void*)g,
                                     (__attribute__((address_space(3))) void*)ldsbase, 16, 0, 0);
}

// ---------------------------------------------------------------------------
// Fused dtype detection: 18 blocks, one per input tensor.
// ---------------------------------------------------------------------------
struct DetectArgs { const void* p[18]; int nw[18]; };

__global__ __launch_bounds__(256) void k_detect_all(DetectArgs a, int* flags)
{
    const int b = blockIdx.x;
    const int t = threadIdx.x;
    __shared__ int cnt[4];
    if (t < 4) cnt[t] = 0;
    __syncthreads();
    if (b == 1) {
        const uint8_t* m = (const uint8_t*)a.p[1];
        int c0 = 0, c1 = 0, c2 = 0, c3 = 0;
        for (int i = t; i < 4096; i += 256) {
            uint8_t v = m[i];
            int mod = i & 3;
            if (v == 0x3F && mod == 1) c0++;
            if (v == 0x3F && mod == 3) c1++;
            if (v == 1 && mod != 0) c2++;
            if (v == 1 && mod == 0) c3++;
        }
        atomicAdd(&cnt[0], c0); atomicAdd(&cnt[1], c1); atomicAdd(&cnt[2], c2); atomicAdd(&cnt[3], c3);
        __syncthreads();
        if (t == 0) {
            int mf;
            if (cnt[0] > 0) mf = 2;
            else if (cnt[1] > 0) mf = 3;
            else if (cnt[2] > 0) mf = 0;
            else if (cnt[3] > 0) mf = 1;
            else mf = 0;
            flags[1] = mf;
        }
    } else {
        const u16* p = (const u16*)a.p[b];
        int nw = a.nw[b];
        int nze = 0, pe = 0, nzo = 0;
        for (int i = t; i < nw; i += 256) {
            u16 w = p[i];
            if (w == 0) continue;
            int e = (w >> 7) & 0xFF;
            bool pl = (e >= 90 && e <= 140);
            if ((i & 1) == 0) { nze++; if (pl) pe++; }
            else nzo++;
        }
        atomicAdd(&cnt[0], nze); atomicAdd(&cnt[1], pe); atomicAdd(&cnt[2], nzo);
        __syncthreads();
        if (t == 0) {
            int f;
            if (cnt[0] > 0)      f = (cnt[1] * 10 >= cnt[0] * 6) ? 2 : 3;
            else if (cnt[2] > 0) f = 3;
            else                 f = 2;
            flags[b] = f;
        }
    }
}

__global__ __launch_bounds__(256) void k_expand_mask(const void* mask, const int* flag, float* mb)
{
    int i = blockIdx.x * 256 + threadIdx.x;
    if (i >= 4096) return;
    int f = *flag;
    bool on;
    if (f == 0)      on = ((const uint8_t*)mask)[i]  != 0;
    else if (f == 1) on = ((const int*)mask)[i]      != 0;
    else if (f == 2) on = ((const u16*)mask)[i]      != 0;
    else             on = ((const uint32_t*)mask)[i] != 0;
    mb[i] = on ? -1e9f : 0.0f;
}

__global__ __launch_bounds__(256) void k_convert_bf(const void* src, u16* dst, int n, const int* flag)
{
    int i = blockIdx.x * 256 + threadIdx.x;
    if (i >= n) return;
    if (*flag == 2) dst[i] = ((const u16*)src)[i];
    else            dst[i] = f2bf(((const float*)src)[i]);
}

// ---------------------------------------------------------------------------
// Fused LDS-tiled weight transposes
// ---------------------------------------------------------------------------
struct TransArgs { const void* src[6]; u16* dst[6]; int R[6]; int C[6]; int flagidx[6]; int tstart[7]; };

__global__ __launch_bounds__(256) void k_transpose_all(TransArgs a, const int* flags)
{
    const int tb = blockIdx.x;
    int s = 0;
    while (tb >= a.tstart[s + 1]) s++;
    const int lt = tb - a.tstart[s];
    const int R = a.R[s], C = a.C[s];
    const int tilesX = C >> 5;
    const int ti = lt / tilesX, tj = lt - ti * tilesX;
    const int r0 = ti * 32, c0 = tj * 32;
    const bool isbf = (flags[a.flagidx[s]] == 2);
    const int t = threadIdx.x;
    const int j = t & 31, i0 = t >> 5;
    __shared__ u16 tile[32][33];
#pragma unroll
    for (int p = 0; p < 4; p++) {
        int r = r0 + i0 + p * 8;
        size_t idx = (size_t)r * C + c0 + j;
        u16 v = isbf ? ((const u16*)a.src[s])[idx] : f2bf(((const float*)a.src[s])[idx]);
        tile[i0 + p * 8][j] = v;
    }
    __syncthreads();
    u16* dst = a.dst[s];
#pragma unroll
    for (int p = 0; p < 4; p++) {
        int c = i0 + p * 8;
        dst[(size_t)(c0 + c) * R + r0 + j] = tile[j][c];
    }
}

// ---------------------------------------------------------------------------
// Fused param converts
// ---------------------------------------------------------------------------
struct ConvArgs { const void* src[10]; int flagidx[10]; int off[10]; int n[10]; };

__global__ __launch_bounds__(256) void k_convert_params(ConvArgs a, const int* flags, float* par)
{
    int i = blockIdx.x * 256 + threadIdx.x;
    if (i >= 11264) return;
    int s = 0;
    while (s < 9 && i >= a.off[s] + a.n[s]) s++;
    int j = i - a.off[s];
    float v;
    if (flags[a.flagidx[s]] == 2) v = bf2f(((const u16*)a.src[s])[j]);
    else                          v = ((const float*)a.src[s])[j];
    par[i] = v;
}

// ---------------------------------------------------------------------------
// MFMA GEMM core, BK=64, async global->LDS staging with XOR-swizzled layout.
// C(M x N) = A(M x K, lda) * Bt(N x K, ldb)^T. fp32 accum. 256 threads.
// ---------------------------------------------------------------------------
template<int BM, int BN, int WR, int WC, int TM, int TN>
DEV void gemm_tile(const u16* __restrict__ A, int lda,
                   const u16* __restrict__ Bt, int ldb, int K,
                   u16* As, u16* Bs, f32x4 (&acc)[TM][TN])
{
    const int t = threadIdx.x;
    const int lane = t & 63;
    const int wave = t >> 6;
    const int wr = wave / WC;
    const int wc = wave % WC;
    const int m16 = lane & 15;
    const int quad = lane >> 4;
    const int lr8 = lane >> 3;                 // 0..7 row within 8-row chunk
    const int lsw = (((lane & 7) ^ lr8) << 3); // swizzled col offset (elements)

#pragma unroll
    for (int i = 0; i < TM; i++)
#pragma unroll
        for (int j = 0; j < TN; j++) {
            acc[i][j][0] = 0.f; acc[i][j][1] = 0.f; acc[i][j][2] = 0.f; acc[i][j][3] = 0.f;
        }

    for (int kb = 0; kb < K; kb += 64) {
#pragma unroll
        for (int i = 0; i < BM / 32; i++) {
            int chunk = wave * (BM / 32) + i;
            int r = chunk * 8 + lr8;
            async16(A + (size_t)r * lda + kb + lsw, As + chunk * 512);
        }
#pragma unroll
        for (int i = 0; i < BN / 32; i++) {
            int chunk = wave * (BN / 32) + i;
            int r = chunk * 8 + lr8;
            async16(Bt + (size_t)r * ldb + kb + lsw, Bs + chunk * 512);
        }
        __syncthreads();   // drains vmcnt (incl. global_load_lds) before LDS reads
#pragma unroll
        for (int ks = 0; ks < 2; ks++) {
            bf16x8 af[TM], bfr[TN];
#pragma unroll
            for (int i = 0; i < TM; i++) {
                int row = wr * TM * 16 + i * 16 + m16;
                int jq = ks * 4 + quad;
                af[i] = *(const bf16x8*)(As + row * 64 + ((jq ^ (row & 7)) << 3));
            }
#pragma unroll
            for (int j = 0; j < TN; j++) {
                int row = wc * TN * 16 + j * 16 + m16;
                int jq = ks * 4 + quad;
                bfr[j] = *(const bf16x8*)(Bs + row * 64 + ((jq ^ (row & 7)) << 3));
            }
#pragma unroll
            for (int i = 0; i < TM; i++)
#pragma unroll
                for (int j = 0; j < TN; j++)
                    acc[i][j] = __builtin_amdgcn_mfma_f32_16x16x32_bf16(af[i], bfr[j], acc[i][j], 0, 0, 0);
        }
        __syncthreads();
    }
}

template<bool RELU>
__global__ __launch_bounds__(256) void k_gemm_std(const u16* __restrict__ A, int lda,
                                                  const u16* __restrict__ Bt, int ldb,
                                                  const float* __restrict__ bias,
                                                  u16* __restrict__ C, int ldc, int K)
{
    __shared__ __align__(16) u16 As[128 * 64];
    __shared__ __align__(16) u16 Bs[128 * 64];
    const u16* Ab = A + (size_t)blockIdx.y * 128 * lda;
    const u16* Bb = Bt + (size_t)blockIdx.x * 128 * ldb;
    f32x4 acc[4][4];
    gemm_tile<128, 128, 2, 2, 4, 4>(Ab, lda, Bb, ldb, K, As, Bs, acc);

    const int t = threadIdx.x, lane = t & 63, wave = t >> 6;
    const int wr = wave >> 1, wc = wave & 1, m16 = lane & 15, quad = lane >> 4;
    const size_t rowBase = (size_t)blockIdx.y * 128 + wr * 64;
    const int colBase = blockIdx.x * 128 + wc * 64;
#pragma unroll
    for (int tm = 0; tm < 4; tm++)
#pragma unroll
        for (int tn = 0; tn < 4; tn++) {
            int col = colBase + tn * 16 + m16;
            float bv = bias ? bias[col] : 0.f;
#pragma unroll
            for (int r = 0; r < 4; r++) {
                size_t row = rowBase + tm * 16 + quad * 4 + r;
                float v = acc[tm][tn][r] + bv;
                if (RELU) v = fmaxf(v, 0.f);
                C[row * (size_t)ldc + col] = f2bf(v);
            }
        }
}

// ---------------------------------------------------------------------------
// Mega-fused attention block: QKV projection + scores + softmax + P*V in ONE
// kernel. Grid 512 (one block per z = bg*16+h), 512 threads = 8 waves.
// Replaces k_gemm_qkv + k_transpose_v + k_attn_fused and removes all 96 MB of
// qproj/kproj/vproj/vT intermediate traffic.
// ---------------------------------------------------------------------------
__global__ __launch_bounds__(512, 2) void k_qkv_attn(const u16* __restrict__ y_c,
                                                     const u16* __restrict__ WqT,
                                                     const u16* __restrict__ WkT,
                                                     const u16* __restrict__ WvT,
                                                     const float* __restrict__ par,
                                                     const float* __restrict__ maskb,
                                                     u16* __restrict__ attedpre)
{
    __shared__ __align__(16) u16 smem[49152];   // 96 KB, phase-aliased
    u16* As  = smem;            // phase1: 256x64 A tile      (16384 u16)
    u16* Wqs = smem + 16384;    // phase1: 64x64              (4096)
    u16* Wks = smem + 20480;    // phase1: 64x64
    u16* Wvs = smem + 24576;    // phase1: 64x64
    u16* Ks  = smem;            // phase2: 256x64 K           (aliases As)
    u16* Vs  = smem + 16384;    // phase2: 64x256 V^T         (aliases W*)
    u16* Pw8 = smem + 32768;    // Q-route + PV chunks: 8 x 2048

    const int z = blockIdx.x;
    const int bg = z >> 4, h = z & 15, hbit = h >> 3, hlow = h & 7;
    const int b = bg & 15, g = bg >> 4;
    const int t = threadIdx.x, lane = t & 63, wave = t >> 6;
    const int m16 = lane & 15, quad = lane >> 4;
    const int lr8 = lane >> 3;
    const int lsw = (((lane & 7) ^ lr8) << 3);

    // A rows: s-th row is y_c row b*512 + 2s + hbit, cols g*512.. -> stride 2048
    const u16* Yb = y_c + (size_t)(b * 512 + hbit) * 1024 + g * 512;

    f32x4 aq[2][4], ak[2][4], av[2][4];
#pragma unroll
    for (int i = 0; i < 2; i++)
#pragma unroll
        for (int j = 0; j < 4; j++) {
            aq[i][j][0]=0.f; aq[i][j][1]=0.f; aq[i][j][2]=0.f; aq[i][j][3]=0.f;
            ak[i][j][0]=0.f; ak[i][j][1]=0.f; ak[i][j][2]=0.f; ak[i][j][3]=0.f;
            av[i][j][0]=0.f; av[i][j][1]=0.f; av[i][j][2]=0.f; av[i][j][3]=0.f;
        }

    // ---- phase 1: projections over 8 K-chunks ----
    for (int c = 0; c < 8; ++c) {
        const int kb = c * 64;
#pragma unroll
        for (int i = 0; i < 4; i++) {
            int chunk = wave * 4 + i;
            int srow = chunk * 8 + lr8;
            async16(Yb + (size_t)srow * 2048 + kb + lsw, As + chunk * 512);
        }
        {
            int row = wave * 8 + lr8;
            const size_t woff = (size_t)(hlow * 64 + row) * 512 + kb + lsw;
            async16(WqT + woff, Wqs + wave * 512);
            async16(WkT + woff, Wks + wave * 512);
            async16(WvT + woff, Wvs + wave * 512);
        }
        __syncthreads();
#pragma unroll
        for (int ks = 0; ks < 2; ks++) {
            const int jq = ks * 4 + quad;
            bf16x8 af[2];
#pragma unroll
            for (int mt = 0; mt < 2; mt++) {
                int row = wave * 32 + mt * 16 + m16;
                af[mt] = *(const bf16x8*)(As + row * 64 + ((jq ^ (row & 7)) << 3));
            }
#pragma unroll
            for (int tn = 0; tn < 4; tn++) {
                int rowb = tn * 16 + m16;
                int offb = rowb * 64 + ((jq ^ (rowb & 7)) << 3);
                bf16x8 wq = *(const bf16x8*)(Wqs + offb);
                bf16x8 wk = *(const bf16x8*)(Wks + offb);
                bf16x8 wv = *(const bf16x8*)(Wvs + offb);
#pragma unroll
                for (int mt = 0; mt < 2; mt++) {
                    aq[mt][tn] = __builtin_amdgcn_mfma_f32_16x16x32_bf16(af[mt], wq, aq[mt][tn], 0, 0, 0);
                    ak[mt][tn] = __builtin_amdgcn_mfma_f32_16x16x32_bf16(af[mt], wk, ak[mt][tn], 0, 0, 0);
                    av[mt][tn] = __builtin_amdgcn_mfma_f32_16x16x32_bf16(af[mt], wv, av[mt][tn], 0, 0, 0);
                }
            }
        }
        __syncthreads();
    }

    // ---- projection epilogues ----
    float bQ[4], bK[4], bV[4];
#pragma unroll
    for (int tn = 0; tn < 4; tn++) {
        int c0 = hlow * 64 + tn * 16 + m16;
        bQ[tn] = par[c0]; bK[tn] = par[512 + c0]; bV[tn] = par[1024 + c0];
    }
    u16* Qw = Pw8 + wave * 2048;   // per-wave 32x64 routing chunk
#pragma unroll
    for (int tm = 0; tm < 2; tm++)
#pragma unroll
        for (int tn = 0; tn < 4; tn++) {
            int dh = tn * 16 + m16;
#pragma unroll
            for (int r = 0; r < 4; r++) {
                int sl = tm * 16 + quad * 4 + r;          // local s 0..31
                int s_ = wave * 32 + sl;                  // global s 0..255
                // K[s][dh] -> Ks, gemm swizzle keyed on s
                Ks[s_ * 64 + ((((dh >> 3) ^ (s_ & 7)) << 3) | (dh & 7))] = f2bf(ak[tm][tn][r] + bK[tn]);
                // V[s][dh] -> Vs[dh][s], PV slot map keyed on (s>>3, dh)
                {
                    int j = s_ >> 3;
                    int slot = (j & 24) | ((j & 7) ^ (dh & 7));
                    Vs[dh * 256 + slot * 8 + (s_ & 7)] = f2bf(av[tm][tn][r] + bV[tn]);
                }
                // Q -> per-wave chunk (C-layout -> A-layout routing)
                Qw[sl * 64 + ((((dh >> 3) ^ (sl & 7)) << 3) | (dh & 7))] = f2bf(aq[tm][tn][r] + bQ[tn]);
            }
        }
    // read Q back as A-frags (wave-private, compiler orders ds write->read)
    bf16x8 qf[2][2];
#pragma unroll
    for (int mt = 0; mt < 2; mt++)
#pragma unroll
        for (int ks = 0; ks < 2; ks++) {
            int row = mt * 16 + m16;
            int jq = ks * 4 + quad;
            qf[mt][ks] = *(const bf16x8*)(Qw + row * 64 + ((jq ^ (row & 7)) << 3));
        }
    float mb[16];
#pragma unroll
    for (int nt = 0; nt < 16; nt++) mb[nt] = maskb[b * 256 + nt * 16 + m16];

    __syncthreads();   // Ks/Vs visible to all waves

    // ---- S = Q K^T ----
    f32x4 s[2][16];
#pragma unroll
    for (int mt = 0; mt < 2; mt++)
#pragma unroll
        for (int nt = 0; nt < 16; nt++) { s[mt][nt][0]=0.f; s[mt][nt][1]=0.f; s[mt][nt][2]=0.f; s[mt][nt][3]=0.f; }
#pragma unroll
    for (int ks = 0; ks < 2; ks++) {
        int jq = ks * 4 + quad;
#pragma unroll
        for (int nt = 0; nt < 16; nt++) {
            int row = nt * 16 + m16;
            bf16x8 kf = *(const bf16x8*)(Ks + row * 64 + ((jq ^ (row & 7)) << 3));
#pragma unroll
            for (int mt = 0; mt < 2; mt++)
                s[mt][nt] = __builtin_amdgcn_mfma_f32_16x16x32_bf16(qf[mt][ks], kf, s[mt][nt], 0, 0, 0);
        }
    }

    // ---- softmax, fully in-wave ----
    float rinv[2][4];
#pragma unroll
    for (int mt = 0; mt < 2; mt++)
#pragma unroll
        for (int r = 0; r < 4; r++) {
            float mm = -3.0e38f;
#pragma unroll
            for (int nt = 0; nt < 16; nt++) {
                float v = s[mt][nt][r] * 0.125f + mb[nt];
                s[mt][nt][r] = v;
                mm = fmaxf(mm, v);
            }
            mm = fmaxf(mm, __shfl_xor(mm, 1));
            mm = fmaxf(mm, __shfl_xor(mm, 2));
            mm = fmaxf(mm, __shfl_xor(mm, 4));
            mm = fmaxf(mm, __shfl_xor(mm, 8));
            float ss = 0.f;
#pragma unroll
            for (int nt = 0; nt < 16; nt++) {
                float e = __expf(s[mt][nt][r] - mm);
                s[mt][nt][r] = e;
                ss += e;
            }
            ss += __shfl_xor(ss, 1);
            ss += __shfl_xor(ss, 2);
            ss += __shfl_xor(ss, 4);
            ss += __shfl_xor(ss, 8);
            rinv[mt][r] = 1.0f / ss;
        }

    // ---- ctx = P V : route P chunks through the per-wave LDS chunk ----
    f32x4 ctx[2][4];
#pragma unroll
    for (int mt = 0; mt < 2; mt++)
#pragma unroll
        for (int dt = 0; dt < 4; dt++) { ctx[mt][dt][0]=0.f; ctx[mt][dt][1]=0.f; ctx[mt][dt][2]=0.f; ctx[mt][dt][3]=0.f; }

#pragma unroll
    for (int kc = 0; kc < 4; kc++) {
#pragma unroll
        for (int mt = 0; mt < 2; mt++)
#pragma unroll
            for (int nl = 0; nl < 4; nl++) {
                int nt = kc * 4 + nl;
#pragma unroll
                for (int r = 0; r < 4; r++) {
                    int row = mt * 16 + quad * 4 + r;
                    int col = nl * 16 + m16;
                    int j = col >> 3, e = col & 7;
                    Qw[row * 64 + (((j ^ (row & 7)) << 3) | e)] = f2bf(s[mt][nt][r] * rinv[mt][r]);
                }
            }
#pragma unroll
        for (int ks = 0; ks < 2; ks++) {
            int jq = ks * 4 + quad;
            bf16x8 pf[2];
#pragma unroll
            for (int mt = 0; mt < 2; mt++) {
                int row = mt * 16 + m16;
                pf[mt] = *(const bf16x8*)(Qw + row * 64 + ((jq ^ (row & 7)) << 3));
            }
#pragma unroll
            for (int dt = 0; dt < 4; dt++) {
                int d = dt * 16 + m16;
                int j = kc * 8 + ks * 4 + quad;
                int slot = (j & 24) | ((j & 7) ^ (d & 7));
                bf16x8 vf = *(const bf16x8*)(Vs + d * 256 + slot * 8);
#pragma unroll
                for (int mt = 0; mt < 2; mt++)
                    ctx[mt][dt] = __builtin_amdgcn_mfma_f32_16x16x32_bf16(pf[mt], vf, ctx[mt][dt], 0, 0, 0);
            }
        }
    }

    // ---- scatter ctx into attedpre (B,L,H): l = 2s+hbit, col = g*512+hlow*64+dh ----
    const int cBase = g * 512 + hlow * 64;
#pragma unroll
    for (int mt = 0; mt < 2; mt++)
#pragma unroll
        for (int dt = 0; dt < 4; dt++) {
            int dh = dt * 16 + m16;
#pragma unroll
            for (int r = 0; r < 4; r++) {
                int sI = wave * 32 + mt * 16 + quad * 4 + r;
                int l = 2 * sI + hbit;
                attedpre[((size_t)b * 512 + l) * 1024 + cBase + dh] = f2bf(ctx[mt][dt][r]);
            }
        }
}

// Fused grouped FFN2: grid (8, 64). x -> (g = x>>2, xn = x&3).
__global__ __launch_bounds__(256) void k_gemm_ffn2(const u16* __restrict__ h1,
                                                   const u16* __restrict__ W2T,
                                                   const float* __restrict__ b2,
                                                   u16* __restrict__ out)
{
    __shared__ __align__(16) u16 As[128 * 64];
    __shared__ __align__(16) u16 Bs[128 * 64];
    const int xi = blockIdx.x;
    const int g = xi >> 2, xn = xi & 3;
    const u16* Ab = h1 + (size_t)blockIdx.y * 128 * 4096 + g * 2048;
    const u16* Bb = W2T + (size_t)xn * 128 * 2048;
    f32x4 acc[4][4];
    gemm_tile<128, 128, 2, 2, 4, 4>(Ab, 4096, Bb, 2048, 2048, As, Bs, acc);

    const int t = threadIdx.x, lane = t & 63, wave = t >> 6;
    const int wr = wave >> 1, wc = wave & 1, m16 = lane & 15, quad = lane >> 4;
    const size_t rowBase = (size_t)blockIdx.y * 128 + wr * 64;
    const int colg = xn * 128 + wc * 64;
#pragma unroll
    for (int tm = 0; tm < 4; tm++)
#pragma unroll
        for (int tn = 0; tn < 4; tn++) {
            int cg = colg + tn * 16 + m16;
            float bv = b2[cg];
#pragma unroll
            for (int r = 0; r < 4; r++) {
                size_t row = rowBase + tm * 16 + quad * 4 + r;
                out[row * 1024 + g * 512 + cg] = f2bf(acc[tm][tn][r] + bv);
            }
        }
}

// out = LN(x1 + x2) * gamma + beta over D=1024; one block per row.
template<int FINAL>
__global__ __launch_bounds__(256) void k_ln(const u16* __restrict__ x1, const u16* __restrict__ x2,
                                            const float* __restrict__ gamma, const float* __restrict__ beta,
                                            void* __restrict__ outv, const int* __restrict__ yflag)
{
    const size_t row = blockIdx.x;
    const int t = threadIdx.x;
    us4 a = *(const us4*)(x1 + row * 1024 + t * 4);
    us4 b = *(const us4*)(x2 + row * 1024 + t * 4);
    float v[4]; float s = 0.f, s2 = 0.f;
#pragma unroll
    for (int i = 0; i < 4; i++) { v[i] = bf2f(a[i]) + bf2f(b[i]); s += v[i]; s2 += v[i] * v[i]; }
#pragma unroll
    for (int off = 32; off > 0; off >>= 1) { s += __shfl_xor(s, off); s2 += __shfl_xor(s2, off); }
    __shared__ float red[8];
    const int lane = t & 63, wave = t >> 6;
    if (lane == 0) { red[wave] = s; red[wave + 4] = s2; }
    __syncthreads();
    s = red[0] + red[1] + red[2] + red[3];
    s2 = red[4] + red[5] + red[6] + red[7];
    float mean = s * (1.0f / 1024.0f);
    float var = fmaxf(s2 * (1.0f / 1024.0f) - mean * mean, 0.0f);
    float rs = rsqrtf(var + 1e-6f);
    float o[4];
#pragma unroll
    for (int i = 0; i < 4; i++) {
        int c = t * 4 + i;
        o[i] = (v[i] - mean) * rs * gamma[c] + beta[c];
    }
    bool f32out = FINAL && yflag && (*yflag == 3);
    if (f32out) {
        float* out = (float*)outv;
#pragma unroll
        for (int i = 0; i < 4; i++) out[row * 1024 + t * 4 + i] = o[i];
    } else {
        u16* out = (u16*)outv;
        us4 ov;
#pragma unroll
        for (int i = 0; i < 4; i++) ov[i] = f2bf(o[i]);
        *(us4*)(out + row * 1024 + t * 4) = ov;
    }
}

// ---------------------------------------------------------------------------
extern "C" void kernel_launch(void* const* d_in, const int* in_sizes, int n_in,
                              void* d_out, int out_size, void* d_ws, size_t ws_size,
                              hipStream_t stream)
{
    (void)in_sizes; (void)n_in; (void)out_size; (void)ws_size;
    const void* y    = d_in[0];
    const void* mask = d_in[1];
    const void* Wv = d_in[2];  const void* bv = d_in[3];
    const void* Wk = d_in[4];  const void* bk = d_in[5];
    const void* Wq = d_in[6];  const void* bq = d_in[7];
    const void* Wm = d_in[8];  const void* bm = d_in[9];
    const void* W1 = d_in[10]; const void* b1 = d_in[11];
    const void* W2 = d_in[12]; const void* b2 = d_in[13];
    const void* g1 = d_in[14]; const void* be1 = d_in[15];
    const void* g2 = d_in[16]; const void* be2 = d_in[17];

    char* ws = (char*)d_ws;
    size_t off = 0;
    auto alloc = [&](size_t bytes) { void* p = ws + off; off = (off + bytes + 255) & ~(size_t)255; return p; };

    int*   flags = (int*)alloc(32 * 4);
    float* maskb = (float*)alloc(16 * 256 * 4);
    float* par   = (float*)alloc(11264 * 4);
    u16* WqT  = (u16*)alloc((size_t)262144 * 2);
    u16* WkT  = (u16*)alloc((size_t)262144 * 2);
    u16* WvT  = (u16*)alloc((size_t)262144 * 2);
    u16* WmT  = (u16*)alloc((size_t)1048576 * 2);
    u16* W1T  = (u16*)alloc((size_t)4194304 * 2);
    u16* W2T  = (u16*)alloc((size_t)1048576 * 2);
    u16* y_c  = (u16*)alloc((size_t)8388608 * 2);
    u16* slotA = (u16*)alloc((size_t)8388608 * 2);   // mergeout
    u16* slotB = (u16*)alloc((size_t)8388608 * 2);   // y1
    u16* slotC = (u16*)alloc((size_t)8388608 * 2);   // ffout
    u16* slotD = (u16*)alloc((size_t)8388608 * 2);   // attedpre
    u16* Pbig  = (u16*)alloc((size_t)33554432 * 2);  // h1 (64 MB region)

    float* p_bm  = par + 1536;
    float* p_b1  = par + 2560;
    float* p_b2  = par + 6656;
    float* p_g1  = par + 7168;
    float* p_be1 = par + 8192;
    float* p_g2  = par + 9216;
    float* p_be2 = par + 10240;

    DetectArgs da;
    {
        const void* srcs[18] = {y, mask, Wv, bv, Wk, bk, Wq, bq, Wm, bm, W1, b1, W2, b2, g1, be1, g2, be2};
        const int   nele[18] = {8388608, 4096, 262144, 512, 262144, 512, 262144, 512, 1048576, 1024,
                                4194304, 4096, 1048576, 512, 1024, 1024, 1024, 1024};
        for (int i = 0; i < 18; i++) { da.p[i] = srcs[i]; da.nw[i] = nele[i] < 4096 ? nele[i] : 4096; }
    }
    k_detect_all<<<18, 256, 0, stream>>>(da, flags);

    k_expand_mask<<<16, 256, 0, stream>>>(mask, flags + 1, maskb);
    k_convert_bf<<<32768, 256, 0, stream>>>(y, y_c, 8388608, flags + 0);

    TransArgs ta;
    {
        const void* s6[6] = {Wq, Wk, Wv, Wm, W1, W2};
        u16* d6[6] = {WqT, WkT, WvT, WmT, W1T, W2T};
        int R6[6] = {512, 512, 512, 1024, 1024, 2048};
        int C6[6] = {512, 512, 512, 1024, 4096, 512};
        int f6[6] = {6, 4, 2, 8, 10, 12};
        int ts[7] = {0, 256, 512, 768, 1792, 5888, 6912};
        for (int i = 0; i < 6; i++) { ta.src[i] = s6[i]; ta.dst[i] = d6[i]; ta.R[i] = R6[i]; ta.C[i] = C6[i]; ta.flagidx[i] = f6[i]; }
        for (int i = 0; i < 7; i++) ta.tstart[i] = ts[i];
    }
    k_transpose_all<<<6912, 256, 0, stream>>>(ta, flags);

    ConvArgs ca;
    {
        const void* s10[10] = {bq, bk, bv, bm, b1, b2, g1, be1, g2, be2};
        int f10[10] = {7, 5, 3, 9, 11, 13, 14, 15, 16, 17};
        int o10[10] = {0, 512, 1024, 1536, 2560, 6656, 7168, 8192, 9216, 10240};
        int n10[10] = {512, 512, 512, 1024, 4096, 512, 1024, 1024, 1024, 1024};
        for (int i = 0; i < 10; i++) { ca.src[i] = s10[i]; ca.flagidx[i] = f10[i]; ca.off[i] = o10[i]; ca.n[i] = n10[i]; }
    }
    k_convert_params<<<44, 256, 0, stream>>>(ca, flags, par);

    u16* attedpre = slotD;
    k_qkv_attn<<<512, 512, 0, stream>>>(y_c, WqT, WkT, WvT, par, maskb, attedpre);

    u16* mergeout = slotA;
    k_gemm_std<false><<<dim3(8, 64), 256, 0, stream>>>(attedpre, 1024, WmT, 1024, p_bm, mergeout, 1024, 1024);

    u16* y1 = slotB;
    k_ln<0><<<8192, 256, 0, stream>>>(y_c, mergeout, p_g1, p_be1, y1, nullptr);

    u16* h1 = Pbig;
    k_gemm_std<true><<<dim3(32, 64), 256, 0, stream>>>(y1, 1024, W1T, 1024, p_b1, h1, 4096, 1024);

    u16* ffout = slotC;
    k_gemm_ffn2<<<dim3(8, 64), 256, 0, stream>>>(h1, W2T, p_b2, ffout);

    k_ln<1><<<8192, 256, 0, stream>>>(y1, ffout, p_g2, p_be2, d_out, flags + 0);
}